// Round 4
// baseline (202.286 us; speedup 1.0000x reference)
//
#include <hip/hip_runtime.h>
#include <math.h>

// B=2, S=2048, D=1024, H=16, DK=64, NUM_BUCKETS=32, MAX_DIST=128, SM_SCALE=0.25
// Softmax runs in log2 domain: Wq pre-scaled by 0.25*log2(e), bias table pre-scaled by log2(e).

typedef _Float16 f16;
typedef _Float16 f16x4 __attribute__((ext_vector_type(4)));
typedef _Float16 f16x8 __attribute__((ext_vector_type(8)));
typedef float f32x4 __attribute__((ext_vector_type(4)));

#define MFMA16(a, b, c) __builtin_amdgcn_mfma_f32_16x16x32_f16((a), (b), (c), 0, 0, 0)

static __device__ __forceinline__ float EXP2(float x) {
  float r;
  asm("v_exp_f32 %0, %1" : "=v"(r) : "v"(x));
  return r;
}

// async global->LDS, 16B per lane; lds base must be wave-uniform (HW adds lane*16)
__device__ __forceinline__ void gload16(const f16* g, f16* l) {
  __builtin_amdgcn_global_load_lds(
      (const __attribute__((address_space(1))) void*)g,
      (__attribute__((address_space(3))) void*)l, 16, 0, 0);
}

// ---------------------------------------------------------------- prep kernels

__global__ __launch_bounds__(256) void cast_x_kernel(const float4* __restrict__ x,
                                                     f16x4* __restrict__ xh) {
  int i = blockIdx.x * 256 + threadIdx.x;
  float4 v = x[i];
  f16x4 o;
  o[0] = (f16)v.x; o[1] = (f16)v.y; o[2] = (f16)v.z; o[3] = (f16)v.w;
  xh[i] = o;
}

// W[k][n] (1024x1024 fp32) -> Wt[z*1024 + n][k] f16; Wq scaled by 0.25*log2e
__global__ void transpose_w_kernel(const float* __restrict__ w0, const float* __restrict__ w1,
                                   const float* __restrict__ w2, const float* __restrict__ w3,
                                   f16* __restrict__ wt) {
  int z = blockIdx.z;
  const float* w = (z == 0) ? w0 : (z == 1) ? w1 : (z == 2) ? w2 : w3;
  float sc = (z == 0) ? 0.36067376022224085f : 1.0f;  // 0.25 * log2(e)
  __shared__ float tile[32][33];
  int tx = threadIdx.x, ty = threadIdx.y;
  int kt = blockIdx.x * 32, nt = blockIdx.y * 32;
#pragma unroll
  for (int i = 0; i < 4; ++i)
    tile[ty + i * 8][tx] = w[(size_t)(kt + ty + i * 8) * 1024 + nt + tx];
  __syncthreads();
#pragma unroll
  for (int i = 0; i < 4; ++i)
    wt[((size_t)z * 1024 + nt + ty + i * 8) * 1024 + kt + tx] = (f16)(tile[tx][ty + i * 8] * sc);
}

// T5 bias table, log2e-scaled, f16, layout [h][4096] with index rp+2048 (rp in [-2047,2047])
__global__ __launch_bounds__(256) void bias_kernel(const float* __restrict__ rel_bias,
                                                   f16* __restrict__ bias_rel) {
  int idx = blockIdx.x * 256 + threadIdx.x;  // 65536 total
  int h = idx >> 12;
  int r = idx & 4095;
  int rp = r - 2048;
  if (rp < -2047) rp = -2047;
  int bucket = (rp > 0) ? 16 : 0;
  int rpa = (rp < 0) ? -rp : rp;
  if (rpa < 8) {
    bucket += rpa;
  } else {
    int large = 8 + (int)(logf((float)rpa / 8.0f) / logf(16.0f) * 8.0f);
    bucket += (large < 15) ? large : 15;
  }
  bias_rel[idx] = (f16)(rel_bias[bucket * 16 + h] * 1.4426950408889634f);
}

// ---------------------------------------------------------------- GEMM 128x128, BK=32
__device__ __forceinline__ void gemm128_core(const f16* __restrict__ A, const f16* __restrict__ Bt,
                                             int mrow, int ncol0, f16* sm /*[2][8192]*/,
                                             f32x4 acc[4][4]) {
  const int t = threadIdx.x;
  const int lane = t & 63, w = t >> 6;
  const int cL = lane & 15, g = lane >> 4;
  const int wr = w >> 1, wc = w & 1;

  const int c0 = w * 128 + lane;
  const int c1 = c0 + 64;
  const int rA0 = c0 >> 2, kA0 = ((c0 & 3) ^ (rA0 & 3)) << 3;
  const int rA1 = c1 >> 2, kA1 = ((c1 & 3) ^ (rA1 & 3)) << 3;
  const f16* gA0 = A + (size_t)(mrow + rA0) * 1024 + kA0;
  const f16* gA1 = A + (size_t)(mrow + rA1) * 1024 + kA1;
  const f16* gB0 = Bt + (size_t)(ncol0 + rA0) * 1024 + kA0;
  const f16* gB1 = Bt + (size_t)(ncol0 + rA1) * 1024 + kA1;
  const int lds0 = (w * 2) * 512, lds1 = (w * 2 + 1) * 512;

#define GSTAGE(buf, k0)                            \
  do {                                             \
    f16* s_ = sm + (buf) * 8192;                   \
    gload16(gA0 + (k0), s_ + lds0);                \
    gload16(gA1 + (k0), s_ + lds1);                \
    gload16(gB0 + (k0), s_ + 4096 + lds0);         \
    gload16(gB1 + (k0), s_ + 4096 + lds1);         \
  } while (0)

  GSTAGE(0, 0);
  __syncthreads();
#pragma unroll 2
  for (int ks = 0; ks < 32; ++ks) {
    const int cur = ks & 1;
    if (ks < 31) GSTAGE(cur ^ 1, (ks + 1) * 32);
    const f16* bA = sm + cur * 8192;
    const f16* bB = bA + 4096;
    f16x8 af[4], bf[4];
#pragma unroll
    for (int m = 0; m < 4; ++m) {
      int r = wr * 64 + m * 16 + cL;
      af[m] = *(const f16x8*)&bA[r * 32 + ((g ^ (r & 3)) << 3)];
    }
#pragma unroll
    for (int n = 0; n < 4; ++n) {
      int r = wc * 64 + n * 16 + cL;
      bf[n] = *(const f16x8*)&bB[r * 32 + ((g ^ (r & 3)) << 3)];
    }
#pragma unroll
    for (int m = 0; m < 4; ++m)
#pragma unroll
      for (int n = 0; n < 4; ++n) acc[m][n] = MFMA16(af[m], bf[n], acc[m][n]);
    __syncthreads();
  }
#undef GSTAGE
}

// QKV projection -> Q,K [b][h][s][dk], V^T [b][h][dk][s]
__global__ __launch_bounds__(256) void gemm_qkv_kernel(const f16* __restrict__ Xh,
                                                       const f16* __restrict__ Wt,
                                                       f16* __restrict__ Qh,
                                                       f16* __restrict__ Kh,
                                                       f16* __restrict__ Vt) {
  __shared__ __align__(16) f16 sm[2][8192];
  int mrow = blockIdx.y * 128, ncol0 = blockIdx.x * 128;
  f32x4 acc[4][4] = {};
  gemm128_core(Xh, Wt, mrow, ncol0, &sm[0][0], acc);
  int lane = threadIdx.x & 63, w = threadIdx.x >> 6;
  int cL = lane & 15, g = lane >> 4;
  int wr = w >> 1, wc = w & 1;
  int which = (ncol0 + wc * 64) >> 10;
#pragma unroll
  for (int m = 0; m < 4; ++m) {
#pragma unroll
    for (int n = 0; n < 4; ++n) {
#pragma unroll
      for (int r = 0; r < 4; ++r) {
        int tt = mrow + wr * 64 + m * 16 + g * 4 + r;
        int b = tt >> 11, s = tt & 2047;
        int col = (ncol0 + wc * 64 + n * 16 + cL) & 1023;
        int hh = col >> 6, dk = col & 63;
        f16 val = (f16)acc[m][n][r];
        if (which == 0)
          Qh[(((size_t)b * 16 + hh) * 2048 + s) * 64 + dk] = val;
        else if (which == 1)
          Kh[(((size_t)b * 16 + hh) * 2048 + s) * 64 + dk] = val;
        else
          Vt[(((size_t)b * 16 + hh) * 64 + dk) * 2048 + s] = val;
      }
    }
  }
}

// Output projection -> fp32 d_out
__global__ __launch_bounds__(256) void gemm_out_kernel(const f16* __restrict__ Oh,
                                                       const f16* __restrict__ WoT,
                                                       float* __restrict__ out) {
  __shared__ __align__(16) f16 sm[2][8192];
  int mrow = blockIdx.y * 128, ncol0 = blockIdx.x * 128;
  f32x4 acc[4][4] = {};
  gemm128_core(Oh, WoT, mrow, ncol0, &sm[0][0], acc);
  int lane = threadIdx.x & 63, w = threadIdx.x >> 6;
  int cL = lane & 15, g = lane >> 4;
  int wr = w >> 1, wc = w & 1;
#pragma unroll
  for (int m = 0; m < 4; ++m)
#pragma unroll
    for (int n = 0; n < 4; ++n)
#pragma unroll
      for (int r = 0; r < 4; ++r) {
        int tt = mrow + wr * 64 + m * 16 + g * 4 + r;
        out[(size_t)tt * 1024 + ncol0 + wc * 64 + n * 16 + cL] = acc[m][n][r];
      }
}

// ---------------------------------------------------------------- attention
// Grid (S/128, B*H), 8 waves (512 thr) each owning 16 q-rows (128/block). K/V tiles
// (64 keys) LDS double-buffered via global_load_lds, shared by all 8 waves.
// Bias slice (f16) staged in LDS; QK^T accumulator initialized with bias.
// Log2-domain softmax with defer-max (THR=8); per-lane partial lsum.
__global__ __launch_bounds__(512) void attn_kernel(const f16* __restrict__ Qh,
                                                   const f16* __restrict__ Kh,
                                                   const f16* __restrict__ Vt,
                                                   const f16* __restrict__ bias_rel,
                                                   f16* __restrict__ Oh) {
  __shared__ __align__(16) f16 sKV[2][8192];  // [buf][ K 4096 | V 4096 ]
  __shared__ __align__(16) char sP[8][2048];  // per-wave P roundtrip
  __shared__ __align__(16) f16 sB[2176];      // bias slice (f16, log2e-scaled)
  int bh = blockIdx.y;
  int h = bh & 15, b = bh >> 4;
  int qt = blockIdx.x * 128;
  int lane = threadIdx.x & 63, wave = threadIdx.x >> 6;
  int cL = lane & 15, g = lane >> 4;
  const size_t bhS = (size_t)bh * 2048;

  // Q A-fragments (Q already scaled by 0.25*log2e)
  const f16* qp = Qh + (bhS + qt + wave * 16 + cL) * 64 + 8 * g;
  f16x8 qa0 = *(const f16x8*)qp;
  f16x8 qa1 = *(const f16x8*)(qp + 32);

  // stage bias slice: sB[j] = bias_rel[h*4096 + (1920 - qt) + j], j in [0,2176)
  // bias(q,k) = sB[k - (q-qt) + 128]
  {
    const float4* gB = (const float4*)(bias_rel + (size_t)h * 4096 + 1920 - qt);
    for (int i = threadIdx.x; i < 272; i += 512) ((float4*)sB)[i] = gB[i];
  }

  // staging: thread stages one 16B K-chunk and one 16B V-chunk per tile
  const int c = threadIdx.x;  // 0..511 chunks
  const int r0 = c >> 3, cc0 = ((c & 7) ^ (r0 & 7)) << 3;
  const f16* gK0 = Kh + (bhS + r0) * 64 + cc0;
  const f16* gV0 = Vt + ((size_t)bh * 64 + r0) * 2048 + cc0;
  const int lds0 = wave * 512;

#define ASTAGE(buf, key0)                          \
  do {                                             \
    f16* s_ = &sKV[buf][0];                        \
    gload16(gK0 + (size_t)(key0) * 64, s_ + lds0); \
    gload16(gV0 + (key0), s_ + 4096 + lds0);       \
  } while (0)

  // lane bias base: sa[n][r] += sB[key0 + n*16 + (3-r) + base]
  const f16* bp = sB + (cL - wave * 16 - g * 4 + 125);

  f32x4 o[4] = {};
  float m[4] = {-INFINITY, -INFINITY, -INFINITY, -INFINITY};
  float lsum[4] = {0.f, 0.f, 0.f, 0.f};
  char* pbase = sP[wave];
  const int sw = (cL & 7) << 4;

  ASTAGE(0, 0);
  __syncthreads();
  for (int kt = 0; kt < 32; ++kt) {
    const int cur = kt & 1;
    if (kt < 31) ASTAGE(cur ^ 1, (kt + 1) * 64);
    const int key0 = kt * 64;
    const f16* kb = &sKV[cur][0];
    const f16* vb = kb + 4096;
    // ---- S2 = bias2 + Q' K^T  (accumulator initialized with bias)
    f32x4 sa[4];
#pragma unroll
    for (int n = 0; n < 4; ++n)
#pragma unroll
      for (int r = 0; r < 4; ++r) sa[n][r] = (float)bp[key0 + n * 16 + 3 - r];
#pragma unroll
    for (int n = 0; n < 4; ++n) {
      int key = n * 16 + cL;
      f16x8 b0 = *(const f16x8*)&kb[key * 64 + ((g ^ (key & 7)) << 3)];
      f16x8 b1 = *(const f16x8*)&kb[key * 64 + (((g + 4) ^ (key & 7)) << 3)];
      sa[n] = MFMA16(qa0, b0, sa[n]);
      sa[n] = MFMA16(qa1, b1, sa[n]);
    }
    // ---- row max (16-lane group reduce)
    float mx[4];
#pragma unroll
    for (int r = 0; r < 4; ++r) {
      float v = fmaxf(fmaxf(sa[0][r], sa[1][r]), fmaxf(sa[2][r], sa[3][r]));
      v = fmaxf(v, __shfl_xor(v, 1));
      v = fmaxf(v, __shfl_xor(v, 2));
      v = fmaxf(v, __shfl_xor(v, 4));
      v = fmaxf(v, __shfl_xor(v, 8));
      mx[r] = v;
    }
    // ---- defer-max: rescale only when a row max grew by > 8 (log2 units)
    bool grow = (mx[0] > m[0] + 8.f) || (mx[1] > m[1] + 8.f) ||
                (mx[2] > m[2] + 8.f) || (mx[3] > m[3] + 8.f);
    if (__any(grow)) {
#pragma unroll
      for (int r = 0; r < 4; ++r) {
        float mn = fmaxf(m[r], mx[r]);
        float corr = EXP2(m[r] - mn);
        lsum[r] *= corr;
        m[r] = mn;
#pragma unroll
        for (int n = 0; n < 4; ++n) o[n][r] *= corr;
      }
    }
    // ---- P = exp2(S2 - m), store to swizzled LDS, accumulate per-lane lsum
#pragma unroll
    for (int n = 0; n < 4; ++n) {
#pragma unroll
      for (int r = 0; r < 4; ++r) {
        float p = EXP2(sa[n][r] - m[r]);
        lsum[r] += p;
        int row = g * 4 + r;
        int byte = row * 128 + (((n * 16 + cL) * 2) ^ ((row & 7) << 4));
        *(f16*)(pbase + byte) = (f16)p;
      }
    }
    asm volatile("s_waitcnt lgkmcnt(0)" ::: "memory");
    int rb = cL * 128;
    f16x8 pa0 = *(const f16x8*)(pbase + rb + ((g * 16) ^ sw));
    f16x8 pa1 = *(const f16x8*)(pbase + rb + ((64 + g * 16) ^ sw));
    // ---- O += P V from LDS (V^T tile [dk][key])
#pragma unroll
    for (int n = 0; n < 4; ++n) {
      int dk = n * 16 + cL;
      f16x8 v0 = *(const f16x8*)&vb[dk * 64 + ((g ^ (dk & 7)) << 3)];
      f16x8 v1 = *(const f16x8*)&vb[dk * 64 + (((g + 4) ^ (dk & 7)) << 3)];
      o[n] = MFMA16(pa0, v0, o[n]);
      o[n] = MFMA16(pa1, v1, o[n]);
    }
    __syncthreads();
  }
#undef ASTAGE
  // ---- epilogue: reduce lsum across the 16-lane group, normalize, store
  const int qrow0 = qt + wave * 16 + g * 4;
#pragma unroll
  for (int r = 0; r < 4; ++r) {
    float s = lsum[r];
    s += __shfl_xor(s, 1);
    s += __shfl_xor(s, 2);
    s += __shfl_xor(s, 4);
    s += __shfl_xor(s, 8);
    float inv = 1.0f / s;
    int q = qrow0 + r;
    size_t rowoff = ((size_t)b * 2048 + q) * 1024 + h * 64;
#pragma unroll
    for (int n = 0; n < 4; ++n)
      Oh[rowoff + n * 16 + cL] = (f16)(o[n][r] * inv);
  }
}

// ---------------------------------------------------------------- launch

extern "C" void kernel_launch(void* const* d_in, const int* in_sizes, int n_in,
                              void* d_out, int out_size, void* d_ws, size_t ws_size,
                              hipStream_t stream) {
  const float* X = (const float*)d_in[0];
  const float* Wq = (const float*)d_in[1];
  const float* Wk = (const float*)d_in[2];
  const float* Wv = (const float*)d_in[3];
  const float* Wo = (const float*)d_in[4];
  const float* relb = (const float*)d_in[5];

  const size_t MB8 = (size_t)8 << 20;
  if (ws_size < 6 * MB8 + (1 << 19)) return;

  char* ws = (char*)d_ws;
  f16* Xh = (f16*)(ws + 0 * MB8);
  f16* Wt = (f16*)(ws + 1 * MB8);
  f16* Qh = (f16*)(ws + 2 * MB8);
  f16* Kh = (f16*)(ws + 3 * MB8);
  f16* Vt = (f16*)(ws + 4 * MB8);
  f16* Oh = (f16*)(ws + 5 * MB8);
  f16* brel = (f16*)(ws + 6 * MB8);  // [16][4096] f16, log2e-scaled

  cast_x_kernel<<<dim3(4096), dim3(256), 0, stream>>>((const float4*)X, (f16x4*)Xh);
  transpose_w_kernel<<<dim3(32, 32, 4), dim3(32, 8), 0, stream>>>(Wq, Wk, Wv, Wo, Wt);
  bias_kernel<<<dim3(256), dim3(256), 0, stream>>>(relb, brel);
  gemm_qkv_kernel<<<dim3(24, 32), dim3(256), 0, stream>>>(Xh, Wt, Qh, Kh, Vt);
  attn_kernel<<<dim3(16, 32), dim3(512), 0, stream>>>(Qh, Kh, Vt, brel, Oh);
  gemm_out_kernel<<<dim3(8, 32), dim3(256), 0, stream>>>(Oh, Wt + (size_t)3072 * 1024,
                                                         (float*)d_out);
}

// Round 5
// 197.183 us; speedup vs baseline: 1.0259x; 1.0259x over previous
//
#include <hip/hip_runtime.h>
#include <math.h>

// B=2, S=2048, D=1024, H=16, DK=64, NUM_BUCKETS=32, MAX_DIST=128, SM_SCALE=0.25
// Softmax runs in log2 domain: Wq pre-scaled by 0.25*log2(e), bias table pre-scaled by log2(e).
// attn uses SWAPPED QK^T (mfma(K,Q)) so each lane owns one q-row -> lane-local softmax.

typedef _Float16 f16;
typedef _Float16 f16x4 __attribute__((ext_vector_type(4)));
typedef _Float16 f16x8 __attribute__((ext_vector_type(8)));
typedef float f32x4 __attribute__((ext_vector_type(4)));

#define MFMA16(a, b, c) __builtin_amdgcn_mfma_f32_16x16x32_f16((a), (b), (c), 0, 0, 0)

static __device__ __forceinline__ float EXP2(float x) {
  float r;
  asm("v_exp_f32 %0, %1" : "=v"(r) : "v"(x));
  return r;
}

// async global->LDS, 16B per lane; lds base must be wave-uniform (HW adds lane*16)
__device__ __forceinline__ void gload16(const f16* g, f16* l) {
  __builtin_amdgcn_global_load_lds(
      (const __attribute__((address_space(1))) void*)g,
      (__attribute__((address_space(3))) void*)l, 16, 0, 0);
}

// ---------------------------------------------------------------- prep kernels

__global__ __launch_bounds__(256) void cast_x_kernel(const float4* __restrict__ x,
                                                     f16x4* __restrict__ xh) {
  int i = blockIdx.x * 256 + threadIdx.x;
  float4 v = x[i];
  f16x4 o;
  o[0] = (f16)v.x; o[1] = (f16)v.y; o[2] = (f16)v.z; o[3] = (f16)v.w;
  xh[i] = o;
}

// W[k][n] (1024x1024 fp32) -> Wt[z*1024 + n][k] f16; Wq scaled by 0.25*log2e
__global__ void transpose_w_kernel(const float* __restrict__ w0, const float* __restrict__ w1,
                                   const float* __restrict__ w2, const float* __restrict__ w3,
                                   f16* __restrict__ wt) {
  int z = blockIdx.z;
  const float* w = (z == 0) ? w0 : (z == 1) ? w1 : (z == 2) ? w2 : w3;
  float sc = (z == 0) ? 0.36067376022224085f : 1.0f;  // 0.25 * log2(e)
  __shared__ float tile[32][33];
  int tx = threadIdx.x, ty = threadIdx.y;
  int kt = blockIdx.x * 32, nt = blockIdx.y * 32;
#pragma unroll
  for (int i = 0; i < 4; ++i)
    tile[ty + i * 8][tx] = w[(size_t)(kt + ty + i * 8) * 1024 + nt + tx];
  __syncthreads();
#pragma unroll
  for (int i = 0; i < 4; ++i)
    wt[((size_t)z * 1024 + nt + ty + i * 8) * 1024 + kt + tx] = (f16)(tile[tx][ty + i * 8] * sc);
}

// T5 bias table, log2e-scaled, f16, layout [h][4096] with index rp+2048 (rp in [-2047,2047])
__global__ __launch_bounds__(256) void bias_kernel(const float* __restrict__ rel_bias,
                                                   f16* __restrict__ bias_rel) {
  int idx = blockIdx.x * 256 + threadIdx.x;  // 65536 total
  int h = idx >> 12;
  int r = idx & 4095;
  int rp = r - 2048;
  if (rp < -2047) rp = -2047;
  int bucket = (rp > 0) ? 16 : 0;
  int rpa = (rp < 0) ? -rp : rp;
  if (rpa < 8) {
    bucket += rpa;
  } else {
    int large = 8 + (int)(logf((float)rpa / 8.0f) / logf(16.0f) * 8.0f);
    bucket += (large < 15) ? large : 15;
  }
  bias_rel[idx] = (f16)(rel_bias[bucket * 16 + h] * 1.4426950408889634f);
}

// ---------------------------------------------------------------- GEMM 128x128, BK=32
__device__ __forceinline__ void gemm128_core(const f16* __restrict__ A, const f16* __restrict__ Bt,
                                             int mrow, int ncol0, f16* sm /*[2][8192]*/,
                                             f32x4 acc[4][4]) {
  const int t = threadIdx.x;
  const int lane = t & 63, w = t >> 6;
  const int cL = lane & 15, g = lane >> 4;
  const int wr = w >> 1, wc = w & 1;

  const int c0 = w * 128 + lane;
  const int c1 = c0 + 64;
  const int rA0 = c0 >> 2, kA0 = ((c0 & 3) ^ (rA0 & 3)) << 3;
  const int rA1 = c1 >> 2, kA1 = ((c1 & 3) ^ (rA1 & 3)) << 3;
  const f16* gA0 = A + (size_t)(mrow + rA0) * 1024 + kA0;
  const f16* gA1 = A + (size_t)(mrow + rA1) * 1024 + kA1;
  const f16* gB0 = Bt + (size_t)(ncol0 + rA0) * 1024 + kA0;
  const f16* gB1 = Bt + (size_t)(ncol0 + rA1) * 1024 + kA1;
  const int lds0 = (w * 2) * 512, lds1 = (w * 2 + 1) * 512;

#define GSTAGE(buf, k0)                            \
  do {                                             \
    f16* s_ = sm + (buf) * 8192;                   \
    gload16(gA0 + (k0), s_ + lds0);                \
    gload16(gA1 + (k0), s_ + lds1);                \
    gload16(gB0 + (k0), s_ + 4096 + lds0);         \
    gload16(gB1 + (k0), s_ + 4096 + lds1);         \
  } while (0)

  GSTAGE(0, 0);
  __syncthreads();
#pragma unroll 2
  for (int ks = 0; ks < 32; ++ks) {
    const int cur = ks & 1;
    if (ks < 31) GSTAGE(cur ^ 1, (ks + 1) * 32);
    const f16* bA = sm + cur * 8192;
    const f16* bB = bA + 4096;
    f16x8 af[4], bf[4];
#pragma unroll
    for (int m = 0; m < 4; ++m) {
      int r = wr * 64 + m * 16 + cL;
      af[m] = *(const f16x8*)&bA[r * 32 + ((g ^ (r & 3)) << 3)];
    }
#pragma unroll
    for (int n = 0; n < 4; ++n) {
      int r = wc * 64 + n * 16 + cL;
      bf[n] = *(const f16x8*)&bB[r * 32 + ((g ^ (r & 3)) << 3)];
    }
#pragma unroll
    for (int m = 0; m < 4; ++m)
#pragma unroll
      for (int n = 0; n < 4; ++n) acc[m][n] = MFMA16(af[m], bf[n], acc[m][n]);
    __syncthreads();
  }
#undef GSTAGE
}

// QKV projection -> Q,K [b][h][s][dk], V^T [b][h][dk][s]
__global__ __launch_bounds__(256) void gemm_qkv_kernel(const f16* __restrict__ Xh,
                                                       const f16* __restrict__ Wt,
                                                       f16* __restrict__ Qh,
                                                       f16* __restrict__ Kh,
                                                       f16* __restrict__ Vt) {
  __shared__ __align__(16) f16 sm[2][8192];
  int mrow = blockIdx.y * 128, ncol0 = blockIdx.x * 128;
  f32x4 acc[4][4] = {};
  gemm128_core(Xh, Wt, mrow, ncol0, &sm[0][0], acc);
  int lane = threadIdx.x & 63, w = threadIdx.x >> 6;
  int cL = lane & 15, g = lane >> 4;
  int wr = w >> 1, wc = w & 1;
  int which = (ncol0 + wc * 64) >> 10;
#pragma unroll
  for (int m = 0; m < 4; ++m) {
#pragma unroll
    for (int n = 0; n < 4; ++n) {
#pragma unroll
      for (int r = 0; r < 4; ++r) {
        int tt = mrow + wr * 64 + m * 16 + g * 4 + r;
        int b = tt >> 11, s = tt & 2047;
        int col = (ncol0 + wc * 64 + n * 16 + cL) & 1023;
        int hh = col >> 6, dk = col & 63;
        f16 val = (f16)acc[m][n][r];
        if (which == 0)
          Qh[(((size_t)b * 16 + hh) * 2048 + s) * 64 + dk] = val;
        else if (which == 1)
          Kh[(((size_t)b * 16 + hh) * 2048 + s) * 64 + dk] = val;
        else
          Vt[(((size_t)b * 16 + hh) * 64 + dk) * 2048 + s] = val;
      }
    }
  }
}

// Output projection -> fp32 d_out
__global__ __launch_bounds__(256) void gemm_out_kernel(const f16* __restrict__ Oh,
                                                       const f16* __restrict__ WoT,
                                                       float* __restrict__ out) {
  __shared__ __align__(16) f16 sm[2][8192];
  int mrow = blockIdx.y * 128, ncol0 = blockIdx.x * 128;
  f32x4 acc[4][4] = {};
  gemm128_core(Oh, WoT, mrow, ncol0, &sm[0][0], acc);
  int lane = threadIdx.x & 63, w = threadIdx.x >> 6;
  int cL = lane & 15, g = lane >> 4;
  int wr = w >> 1, wc = w & 1;
#pragma unroll
  for (int m = 0; m < 4; ++m)
#pragma unroll
    for (int n = 0; n < 4; ++n)
#pragma unroll
      for (int r = 0; r < 4; ++r) {
        int tt = mrow + wr * 64 + m * 16 + g * 4 + r;
        out[(size_t)tt * 1024 + ncol0 + wc * 64 + n * 16 + cL] = acc[m][n][r];
      }
}

// ---------------------------------------------------------------- attention
// Grid (S/64, B*H), 4 waves/block each owning 16 q-rows. K/V tiles LDS double-buffered.
// SWAPPED QK^T: sa[n][r] = S[q = lane&15][key = key0 + n*16 + g*4 + r] -> softmax is
// lane-local (per-lane m/lsum for row q=cL). Bias C-init from LDS slice. Defer-max THR=8.
// P packed as f16x4 (4x ds_write_b64), PV unchanged.
__global__ __launch_bounds__(256) void attn_kernel(const f16* __restrict__ Qh,
                                                   const f16* __restrict__ Kh,
                                                   const f16* __restrict__ Vt,
                                                   const f16* __restrict__ bias_rel,
                                                   f16* __restrict__ Oh) {
  __shared__ __align__(16) f16 sKV[2][8192];  // [buf][ K 4096 | V 4096 ]
  __shared__ __align__(16) char sP[4][2048];  // per-wave P roundtrip
  __shared__ __align__(16) f16 sB[2176];      // bias slice (f16, log2e-scaled)
  int bh = blockIdx.y;
  int h = bh & 15, b = bh >> 4;
  int qt = blockIdx.x * 64;
  int lane = threadIdx.x & 63, wave = threadIdx.x >> 6;
  int cL = lane & 15, g = lane >> 4;
  const size_t bhS = (size_t)bh * 2048;

  // Q fragments (Q already scaled by 0.25*log2e); used as the B-operand of swapped QK^T
  const f16* qp = Qh + (bhS + qt + wave * 16 + cL) * 64 + 8 * g;
  f16x8 qa0 = *(const f16x8*)qp;
  f16x8 qa1 = *(const f16x8*)(qp + 32);

  // stage bias slice: sB[j] = bias_rel[h*4096 + (1984 - qt) + j], j in [0,2176)
  // bias(q,k) = sB[k - (q - qt) + 64]
  {
    const float4* gB = (const float4*)(bias_rel + (size_t)h * 4096 + 1984 - qt);
    for (int i = threadIdx.x; i < 272; i += 256) ((float4*)sB)[i] = gB[i];
  }

  // K/V staging descriptors (chunk = 16B = 8 f16)
  const int c0 = wave * 128 + lane;
  const int c1 = c0 + 64;
  const int r0 = c0 >> 3, cc0 = ((c0 & 7) ^ (r0 & 7)) << 3;
  const int r1 = c1 >> 3, cc1 = ((c1 & 7) ^ (r1 & 7)) << 3;
  const f16* gK0 = Kh + (bhS + r0) * 64 + cc0;
  const f16* gK1 = Kh + (bhS + r1) * 64 + cc1;
  const f16* gV0 = Vt + ((size_t)bh * 64 + r0) * 2048 + cc0;
  const f16* gV1 = Vt + ((size_t)bh * 64 + r1) * 2048 + cc1;
  const int lds0 = (wave * 2) * 512, lds1 = (wave * 2 + 1) * 512;

#define ASTAGE(buf, key0)                          \
  do {                                             \
    f16* s_ = &sKV[buf][0];                        \
    gload16(gK0 + (size_t)(key0) * 64, s_ + lds0); \
    gload16(gK1 + (size_t)(key0) * 64, s_ + lds1); \
    gload16(gV0 + (key0), s_ + 4096 + lds0);       \
    gload16(gV1 + (key0), s_ + 4096 + lds1);       \
  } while (0)

  const int wq = wave * 16 + cL;  // this lane's q-row within block

  f32x4 o[4] = {};
  float m = -INFINITY, lsum = 0.f;
  char* pbase = sP[wave];
  const int sw = (cL & 7) << 4;
  const int pw0 = cL * 128;

  ASTAGE(0, 0);
  __syncthreads();
  for (int kt = 0; kt < 32; ++kt) {
    const int cur = kt & 1;
    if (kt < 31) ASTAGE(cur ^ 1, (kt + 1) * 64);
    const int key0 = kt * 64;
    const f16* kb = &sKV[cur][0];
    const f16* vb = kb + 4096;
    // ---- bias C-init: sa[n][r] = bias(q=cL-row, key0+n*16+g*4+r)
    const int bbase = key0 + g * 4 - wq + 64;
    f32x4 sa[4];
#pragma unroll
    for (int n = 0; n < 4; ++n)
#pragma unroll
      for (int r = 0; r < 4; ++r) sa[n][r] = (float)sB[bbase + n * 16 + r];
    // ---- S^T = K Q^T (swapped operands: col=q, row=key)
    __builtin_amdgcn_s_setprio(1);
#pragma unroll
    for (int n = 0; n < 4; ++n) {
      int key = n * 16 + cL;
      f16x8 b0 = *(const f16x8*)&kb[key * 64 + ((g ^ (key & 7)) << 3)];
      f16x8 b1 = *(const f16x8*)&kb[key * 64 + (((g + 4) ^ (key & 7)) << 3)];
      sa[n] = MFMA16(b0, qa0, sa[n]);
      sa[n] = MFMA16(b1, qa1, sa[n]);
    }
    __builtin_amdgcn_s_setprio(0);
    // ---- lane-local row max over this lane's 16 k-values
    float mx = fmaxf(fmaxf(fmaxf(sa[0][0], sa[0][1]), fmaxf(sa[0][2], sa[0][3])),
                     fmaxf(fmaxf(sa[1][0], sa[1][1]), fmaxf(sa[1][2], sa[1][3])));
    mx = fmaxf(mx, fmaxf(fmaxf(fmaxf(sa[2][0], sa[2][1]), fmaxf(sa[2][2], sa[2][3])),
                         fmaxf(fmaxf(sa[3][0], sa[3][1]), fmaxf(sa[3][2], sa[3][3]))));
    mx = fmaxf(mx, __shfl_xor(mx, 16));
    mx = fmaxf(mx, __shfl_xor(mx, 32));
    // ---- defer-max: rescale only when row max grew by > 8 (log2 units)
    if (__any(mx > m + 8.f)) {
      float mn = fmaxf(m, mx);
      float corr = EXP2(m - mn);
      lsum *= corr;
      m = mn;
      float cr0 = __shfl(corr, g * 4 + 0);
      float cr1 = __shfl(corr, g * 4 + 1);
      float cr2 = __shfl(corr, g * 4 + 2);
      float cr3 = __shfl(corr, g * 4 + 3);
#pragma unroll
      for (int n = 0; n < 4; ++n) {
        o[n][0] *= cr0; o[n][1] *= cr1; o[n][2] *= cr2; o[n][3] *= cr3;
      }
    }
    // ---- P = exp2(S - m): lane-local lsum; pack 4 contiguous k -> ds_write_b64
    f16x4 pk[4];
#pragma unroll
    for (int n = 0; n < 4; ++n) {
#pragma unroll
      for (int r = 0; r < 4; ++r) {
        float p = EXP2(sa[n][r] - m);
        lsum += p;
        pk[n][r] = (f16)p;
      }
    }
#pragma unroll
    for (int n = 0; n < 4; ++n)
      *(f16x4*)(pbase + pw0 + ((n * 32 + g * 8) ^ sw)) = pk[n];
    asm volatile("s_waitcnt lgkmcnt(0)" ::: "memory");
    f16x8 pa0 = *(const f16x8*)(pbase + pw0 + ((g * 16) ^ sw));
    f16x8 pa1 = *(const f16x8*)(pbase + pw0 + ((64 + g * 16) ^ sw));
    // ---- O += P V from LDS (V^T tile [dk][key])
    __builtin_amdgcn_s_setprio(1);
#pragma unroll
    for (int n = 0; n < 4; ++n) {
      int dk = n * 16 + cL;
      f16x8 v0 = *(const f16x8*)&vb[dk * 64 + ((g ^ (dk & 7)) << 3)];
      f16x8 v1 = *(const f16x8*)&vb[dk * 64 + (((g + 4) ^ (dk & 7)) << 3)];
      o[n] = MFMA16(pa0, v0, o[n]);
      o[n] = MFMA16(pa1, v1, o[n]);
    }
    __builtin_amdgcn_s_setprio(0);
    __syncthreads();
  }
#undef ASTAGE
  // ---- epilogue: complete lsum for row q=cL, redistribute inv to C-layout rows, store
  float s = lsum;
  s += __shfl_xor(s, 16);
  s += __shfl_xor(s, 32);
  float inv = 1.0f / s;
  float iv0 = __shfl(inv, g * 4 + 0);
  float iv1 = __shfl(inv, g * 4 + 1);
  float iv2 = __shfl(inv, g * 4 + 2);
  float iv3 = __shfl(inv, g * 4 + 3);
  const int qrow0 = qt + wave * 16 + g * 4;
  size_t rowoff = ((size_t)b * 2048 + qrow0) * 1024 + h * 64;
#pragma unroll
  for (int n = 0; n < 4; ++n) {
    Oh[rowoff + 0 * 1024 + n * 16 + cL] = (f16)(o[n][0] * iv0);
    Oh[rowoff + 1 * 1024 + n * 16 + cL] = (f16)(o[n][1] * iv1);
    Oh[rowoff + 2 * 1024 + n * 16 + cL] = (f16)(o[n][2] * iv2);
    Oh[rowoff + 3 * 1024 + n * 16 + cL] = (f16)(o[n][3] * iv3);
  }
}

// ---------------------------------------------------------------- launch

extern "C" void kernel_launch(void* const* d_in, const int* in_sizes, int n_in,
                              void* d_out, int out_size, void* d_ws, size_t ws_size,
                              hipStream_t stream) {
  const float* X = (const float*)d_in[0];
  const float* Wq = (const float*)d_in[1];
  const float* Wk = (const float*)d_in[2];
  const float* Wv = (const float*)d_in[3];
  const float* Wo = (const float*)d_in[4];
  const float* relb = (const float*)d_in[5];

  const size_t MB8 = (size_t)8 << 20;
  if (ws_size < 6 * MB8 + (1 << 19)) return;

  char* ws = (char*)d_ws;
  f16* Xh = (f16*)(ws + 0 * MB8);
  f16* Wt = (f16*)(ws + 1 * MB8);
  f16* Qh = (f16*)(ws + 2 * MB8);
  f16* Kh = (f16*)(ws + 3 * MB8);
  f16* Vt = (f16*)(ws + 4 * MB8);
  f16* Oh = (f16*)(ws + 5 * MB8);
  f16* brel = (f16*)(ws + 6 * MB8);  // [16][4096] f16, log2e-scaled

  cast_x_kernel<<<dim3(4096), dim3(256), 0, stream>>>((const float4*)X, (f16x4*)Xh);
  transpose_w_kernel<<<dim3(32, 32, 4), dim3(32, 8), 0, stream>>>(Wq, Wk, Wv, Wo, Wt);
  bias_kernel<<<dim3(256), dim3(256), 0, stream>>>(relb, brel);
  gemm_qkv_kernel<<<dim3(24, 32), dim3(256), 0, stream>>>(Xh, Wt, Qh, Kh, Vt);
  attn_kernel<<<dim3(32, 32), dim3(256), 0, stream>>>(Qh, Kh, Vt, brel, Oh);
  gemm_out_kernel<<<dim3(8, 32), dim3(256), 0, stream>>>(Oh, Wt + (size_t)3072 * 1024,
                                                         (float*)d_out);
}

// Round 6
// 154.837 us; speedup vs baseline: 1.3064x; 1.2735x over previous
//
#include <hip/hip_runtime.h>
#include <math.h>

// B=2, S=2048, D=1024, H=16, DK=64, NUM_BUCKETS=32, MAX_DIST=128, SM_SCALE=0.25
// Softmax in log2 domain: Wq pre-scaled by 0.25*log2(e), bias table pre-scaled by log2(e).
// attn: SWAPPED QK^T (mfma(K,Q)) -> lane-local softmax; 32 q-rows/wave (2 subtiles);
// T5 bucket saturation (|k-q|>=91 -> per-head constant bias) skips table on 26/32 tiles.

typedef _Float16 f16;
typedef _Float16 f16x4 __attribute__((ext_vector_type(4)));
typedef _Float16 f16x8 __attribute__((ext_vector_type(8)));
typedef float f32x4 __attribute__((ext_vector_type(4)));

#define MFMA16(a, b, c) __builtin_amdgcn_mfma_f32_16x16x32_f16((a), (b), (c), 0, 0, 0)

static __device__ __forceinline__ float EXP2(float x) {
  float r;
  asm("v_exp_f32 %0, %1" : "=v"(r) : "v"(x));
  return r;
}

// async global->LDS, 16B per lane; lds base must be wave-uniform (HW adds lane*16)
__device__ __forceinline__ void gload16(const f16* g, f16* l) {
  __builtin_amdgcn_global_load_lds(
      (const __attribute__((address_space(1))) void*)g,
      (__attribute__((address_space(3))) void*)l, 16, 0, 0);
}

// ---------------------------------------------------------------- prep kernels

__global__ __launch_bounds__(256) void cast_x_kernel(const float4* __restrict__ x,
                                                     f16x4* __restrict__ xh) {
  int i = blockIdx.x * 256 + threadIdx.x;
  float4 v = x[i];
  f16x4 o;
  o[0] = (f16)v.x; o[1] = (f16)v.y; o[2] = (f16)v.z; o[3] = (f16)v.w;
  xh[i] = o;
}

// W[k][n] (1024x1024 fp32) -> Wt[z*1024 + n][k] f16; Wq scaled by 0.25*log2e
__global__ void transpose_w_kernel(const float* __restrict__ w0, const float* __restrict__ w1,
                                   const float* __restrict__ w2, const float* __restrict__ w3,
                                   f16* __restrict__ wt) {
  int z = blockIdx.z;
  const float* w = (z == 0) ? w0 : (z == 1) ? w1 : (z == 2) ? w2 : w3;
  float sc = (z == 0) ? 0.36067376022224085f : 1.0f;  // 0.25 * log2(e)
  __shared__ float tile[32][33];
  int tx = threadIdx.x, ty = threadIdx.y;
  int kt = blockIdx.x * 32, nt = blockIdx.y * 32;
#pragma unroll
  for (int i = 0; i < 4; ++i)
    tile[ty + i * 8][tx] = w[(size_t)(kt + ty + i * 8) * 1024 + nt + tx];
  __syncthreads();
#pragma unroll
  for (int i = 0; i < 4; ++i)
    wt[((size_t)z * 1024 + nt + ty + i * 8) * 1024 + kt + tx] = (f16)(tile[tx][ty + i * 8] * sc);
}

// T5 bias table, log2e-scaled, f16, layout [h][4096] with index rp+2048 (rp in [-2047,2047])
__global__ __launch_bounds__(256) void bias_kernel(const float* __restrict__ rel_bias,
                                                   f16* __restrict__ bias_rel) {
  int idx = blockIdx.x * 256 + threadIdx.x;  // 65536 total
  int h = idx >> 12;
  int r = idx & 4095;
  int rp = r - 2048;
  if (rp < -2047) rp = -2047;
  int bucket = (rp > 0) ? 16 : 0;
  int rpa = (rp < 0) ? -rp : rp;
  if (rpa < 8) {
    bucket += rpa;
  } else {
    int large = 8 + (int)(logf((float)rpa / 8.0f) / logf(16.0f) * 8.0f);
    bucket += (large < 15) ? large : 15;
  }
  bias_rel[idx] = (f16)(rel_bias[bucket * 16 + h] * 1.4426950408889634f);
}

// ---------------------------------------------------------------- GEMM 128x128, BK=32
__device__ __forceinline__ void gemm128_core(const f16* __restrict__ A, const f16* __restrict__ Bt,
                                             int mrow, int ncol0, f16* sm /*[2][8192]*/,
                                             f32x4 acc[4][4]) {
  const int t = threadIdx.x;
  const int lane = t & 63, w = t >> 6;
  const int cL = lane & 15, g = lane >> 4;
  const int wr = w >> 1, wc = w & 1;

  const int c0 = w * 128 + lane;
  const int c1 = c0 + 64;
  const int rA0 = c0 >> 2, kA0 = ((c0 & 3) ^ (rA0 & 3)) << 3;
  const int rA1 = c1 >> 2, kA1 = ((c1 & 3) ^ (rA1 & 3)) << 3;
  const f16* gA0 = A + (size_t)(mrow + rA0) * 1024 + kA0;
  const f16* gA1 = A + (size_t)(mrow + rA1) * 1024 + kA1;
  const f16* gB0 = Bt + (size_t)(ncol0 + rA0) * 1024 + kA0;
  const f16* gB1 = Bt + (size_t)(ncol0 + rA1) * 1024 + kA1;
  const int lds0 = (w * 2) * 512, lds1 = (w * 2 + 1) * 512;

#define GSTAGE(buf, k0)                            \
  do {                                             \
    f16* s_ = sm + (buf) * 8192;                   \
    gload16(gA0 + (k0), s_ + lds0);                \
    gload16(gA1 + (k0), s_ + lds1);                \
    gload16(gB0 + (k0), s_ + 4096 + lds0);         \
    gload16(gB1 + (k0), s_ + 4096 + lds1);         \
  } while (0)

  GSTAGE(0, 0);
  __syncthreads();
#pragma unroll 2
  for (int ks = 0; ks < 32; ++ks) {
    const int cur = ks & 1;
    if (ks < 31) GSTAGE(cur ^ 1, (ks + 1) * 32);
    const f16* bA = sm + cur * 8192;
    const f16* bB = bA + 4096;
    f16x8 af[4], bf[4];
#pragma unroll
    for (int m = 0; m < 4; ++m) {
      int r = wr * 64 + m * 16 + cL;
      af[m] = *(const f16x8*)&bA[r * 32 + ((g ^ (r & 3)) << 3)];
    }
#pragma unroll
    for (int n = 0; n < 4; ++n) {
      int r = wc * 64 + n * 16 + cL;
      bf[n] = *(const f16x8*)&bB[r * 32 + ((g ^ (r & 3)) << 3)];
    }
#pragma unroll
    for (int m = 0; m < 4; ++m)
#pragma unroll
      for (int n = 0; n < 4; ++n) acc[m][n] = MFMA16(af[m], bf[n], acc[m][n]);
    __syncthreads();
  }
#undef GSTAGE
}

// QKV projection -> Q,K [b][h][s][dk], V^T [b][h][dk][s]
__global__ __launch_bounds__(256) void gemm_qkv_kernel(const f16* __restrict__ Xh,
                                                       const f16* __restrict__ Wt,
                                                       f16* __restrict__ Qh,
                                                       f16* __restrict__ Kh,
                                                       f16* __restrict__ Vt) {
  __shared__ __align__(16) f16 sm[2][8192];
  int mrow = blockIdx.y * 128, ncol0 = blockIdx.x * 128;
  f32x4 acc[4][4] = {};
  gemm128_core(Xh, Wt, mrow, ncol0, &sm[0][0], acc);
  int lane = threadIdx.x & 63, w = threadIdx.x >> 6;
  int cL = lane & 15, g = lane >> 4;
  int wr = w >> 1, wc = w & 1;
  int which = (ncol0 + wc * 64) >> 10;
#pragma unroll
  for (int m = 0; m < 4; ++m) {
#pragma unroll
    for (int n = 0; n < 4; ++n) {
#pragma unroll
      for (int r = 0; r < 4; ++r) {
        int tt = mrow + wr * 64 + m * 16 + g * 4 + r;
        int b = tt >> 11, s = tt & 2047;
        int col = (ncol0 + wc * 64 + n * 16 + cL) & 1023;
        int hh = col >> 6, dk = col & 63;
        f16 val = (f16)acc[m][n][r];
        if (which == 0)
          Qh[(((size_t)b * 16 + hh) * 2048 + s) * 64 + dk] = val;
        else if (which == 1)
          Kh[(((size_t)b * 16 + hh) * 2048 + s) * 64 + dk] = val;
        else
          Vt[(((size_t)b * 16 + hh) * 64 + dk) * 2048 + s] = val;
      }
    }
  }
}

// Output projection -> fp32 d_out
__global__ __launch_bounds__(256) void gemm_out_kernel(const f16* __restrict__ Oh,
                                                       const f16* __restrict__ WoT,
                                                       float* __restrict__ out) {
  __shared__ __align__(16) f16 sm[2][8192];
  int mrow = blockIdx.y * 128, ncol0 = blockIdx.x * 128;
  f32x4 acc[4][4] = {};
  gemm128_core(Oh, WoT, mrow, ncol0, &sm[0][0], acc);
  int lane = threadIdx.x & 63, w = threadIdx.x >> 6;
  int cL = lane & 15, g = lane >> 4;
  int wr = w >> 1, wc = w & 1;
#pragma unroll
  for (int m = 0; m < 4; ++m)
#pragma unroll
    for (int n = 0; n < 4; ++n)
#pragma unroll
      for (int r = 0; r < 4; ++r) {
        int tt = mrow + wr * 64 + m * 16 + g * 4 + r;
        out[(size_t)tt * 1024 + ncol0 + wc * 64 + n * 16 + cL] = acc[m][n][r];
      }
}

// ---------------------------------------------------------------- attention
// Grid (S/128, B*H), 4 waves/block, each wave 32 q-rows (2x16 subtiles). K/V (64-key)
// tiles LDS double-buffered, shared by the 4 waves; K/V frags reused across subtiles.
// Swapped QK^T; bias: saturated tiles (|k-q|>=91 guaranteed) use per-head constant,
// near tiles read LDS table slice. Defer-max THR=8 (log2 units).
__global__ __launch_bounds__(256) void attn_kernel(const f16* __restrict__ Qh,
                                                   const f16* __restrict__ Kh,
                                                   const f16* __restrict__ Vt,
                                                   const f16* __restrict__ bias_rel,
                                                   f16* __restrict__ Oh) {
  __shared__ __align__(16) f16 sKV[2][8192];  // [buf][ K 4096 | V 4096 ] f16
  __shared__ __align__(16) char sP[4][4096];  // per-wave P roundtrip (2 subtiles x 2KB)
  __shared__ __align__(16) f16 sB[2176];      // bias slice (f16, log2e-scaled)
  int bh = blockIdx.y;
  int h = bh & 15, b = bh >> 4;
  int qt = blockIdx.x * 128;
  int t = threadIdx.x;
  int lane = t & 63, wave = t >> 6;
  int cL = lane & 15, g = lane >> 4;
  const size_t bhS = (size_t)bh * 2048;
  const int qbase = qt + wave * 32;

  // Q fragments for both 16-row subtiles (Q pre-scaled by 0.25*log2e)
  const f16* qp = Qh + (bhS + qbase + cL) * 64 + 8 * g;
  f16x8 qa00 = *(const f16x8*)qp;            // u=0, k 0..31 slice
  f16x8 qa01 = *(const f16x8*)(qp + 32);     // u=0, k 32..63 slice
  f16x8 qa10 = *(const f16x8*)(qp + 1024);   // u=1 (row +16)
  f16x8 qa11 = *(const f16x8*)(qp + 1056);

  // far-tile constants: bucket saturates for |rp| >= 91
  float cpos = (float)bias_rel[(size_t)h * 4096 + 4095];  // rp = +2047
  float cneg = (float)bias_rel[(size_t)h * 4096 + 1];     // rp = -2047

  // stage bias slice: sB[j] = bias_rel[h*4096 + 1920 - qt + j]; bias(q,k)=sB[k-(q-qt)+128]
  {
    const float4* gB = (const float4*)(bias_rel + (size_t)h * 4096 + 1920 - qt);
    for (int i = t; i < 272; i += 256) ((float4*)sB)[i] = gB[i];
  }

  // K/V staging: 512 16B chunks each for K,V per tile; thread stages chunks t and t+256
  const int rK0 = t >> 3, ccK0 = ((t & 7) ^ (rK0 & 7)) << 3;
  const int rK1 = rK0 + 32, ccK1 = ((t & 7) ^ (rK1 & 7)) << 3;
  const f16* gK0 = Kh + (bhS + rK0) * 64 + ccK0;
  const f16* gK1 = Kh + (bhS + rK1) * 64 + ccK1;
  const f16* gV0 = Vt + ((size_t)bh * 64 + rK0) * 2048 + ccK0;
  const f16* gV1 = Vt + ((size_t)bh * 64 + rK1) * 2048 + ccK1;
  const int ldsA = wave * 512, ldsB = wave * 512 + 2048;

#define ASTAGE(buf, key0)                           \
  do {                                              \
    f16* s_ = &sKV[buf][0];                         \
    gload16(gK0 + (size_t)(key0) * 64, s_ + ldsA);  \
    gload16(gK1 + (size_t)(key0) * 64, s_ + ldsB);  \
    gload16(gV0 + (key0), s_ + 4096 + ldsA);        \
    gload16(gV1 + (key0), s_ + 4096 + ldsB);        \
  } while (0)

  f32x4 o0[4] = {}, o1[4] = {};
  float m0 = -INFINITY, m1 = -INFINITY, lsum0 = 0.f, lsum1 = 0.f;
  char* pbase = sP[wave];
  const int sw = (cL & 7) << 4;
  const int pw0 = cL * 128;

  ASTAGE(0, 0);
  __syncthreads();
  for (int kt = 0; kt < 32; ++kt) {
    const int cur = kt & 1;
    if (kt < 31) ASTAGE(cur ^ 1, (kt + 1) * 64);
    const int key0 = kt * 64;
    const f16* kb = &sKV[cur][0];
    const f16* vb = kb + 4096;
    const int dkt = key0 - qt;

    // ---- load K fragments once (shared by both q-subtiles)
    f16x8 kf0[4], kf1[4];
#pragma unroll
    for (int n = 0; n < 4; ++n) {
      int key = n * 16 + cL;
      kf0[n] = *(const f16x8*)&kb[key * 64 + ((g ^ (key & 7)) << 3)];
      kf1[n] = *(const f16x8*)&kb[key * 64 + (((g + 4) ^ (key & 7)) << 3)];
    }
    // ---- bias C-init
    f32x4 sa0[4], sa1[4];
    if (dkt >= 256 || dkt <= -192) {
      float c = (dkt > 0) ? cpos : cneg;
#pragma unroll
      for (int n = 0; n < 4; ++n)
#pragma unroll
        for (int r = 0; r < 4; ++r) { sa0[n][r] = c; sa1[n][r] = c; }
    } else {
      const int bb0 = key0 + g * 4 + 128 - wave * 32 - cL;
      const int bb1 = bb0 - 16;
#pragma unroll
      for (int n = 0; n < 4; ++n)
#pragma unroll
        for (int r = 0; r < 4; ++r) {
          sa0[n][r] = (float)sB[bb0 + n * 16 + r];
          sa1[n][r] = (float)sB[bb1 + n * 16 + r];
        }
    }
    // ---- S^T = K Q^T for both subtiles (swapped operands: col=q, row=key)
    __builtin_amdgcn_s_setprio(1);
#pragma unroll
    for (int n = 0; n < 4; ++n) {
      sa0[n] = MFMA16(kf0[n], qa00, sa0[n]);
      sa0[n] = MFMA16(kf1[n], qa01, sa0[n]);
      sa1[n] = MFMA16(kf0[n], qa10, sa1[n]);
      sa1[n] = MFMA16(kf1[n], qa11, sa1[n]);
    }
    __builtin_amdgcn_s_setprio(0);
    // ---- lane-local row max per subtile
    float mx0 = fmaxf(fmaxf(fmaxf(sa0[0][0], sa0[0][1]), fmaxf(sa0[0][2], sa0[0][3])),
                      fmaxf(fmaxf(sa0[1][0], sa0[1][1]), fmaxf(sa0[1][2], sa0[1][3])));
    mx0 = fmaxf(mx0, fmaxf(fmaxf(fmaxf(sa0[2][0], sa0[2][1]), fmaxf(sa0[2][2], sa0[2][3])),
                           fmaxf(fmaxf(sa0[3][0], sa0[3][1]), fmaxf(sa0[3][2], sa0[3][3]))));
    float mx1 = fmaxf(fmaxf(fmaxf(sa1[0][0], sa1[0][1]), fmaxf(sa1[0][2], sa1[0][3])),
                      fmaxf(fmaxf(sa1[1][0], sa1[1][1]), fmaxf(sa1[1][2], sa1[1][3])));
    mx1 = fmaxf(mx1, fmaxf(fmaxf(fmaxf(sa1[2][0], sa1[2][1]), fmaxf(sa1[2][2], sa1[2][3])),
                           fmaxf(fmaxf(sa1[3][0], sa1[3][1]), fmaxf(sa1[3][2], sa1[3][3]))));
    mx0 = fmaxf(mx0, __shfl_xor(mx0, 16));
    mx0 = fmaxf(mx0, __shfl_xor(mx0, 32));
    mx1 = fmaxf(mx1, __shfl_xor(mx1, 16));
    mx1 = fmaxf(mx1, __shfl_xor(mx1, 32));
    // ---- defer-max: rescale only when a row max grew by > 8 (log2 units)
    if (__any((mx0 > m0 + 8.f) || (mx1 > m1 + 8.f))) {
      float mn0 = fmaxf(m0, mx0), mn1 = fmaxf(m1, mx1);
      float corr0 = EXP2(m0 - mn0), corr1 = EXP2(m1 - mn1);
      lsum0 *= corr0; lsum1 *= corr1;
      m0 = mn0; m1 = mn1;
#pragma unroll
      for (int r = 0; r < 4; ++r) {
        float c0 = __shfl(corr0, g * 4 + r);
        float c1 = __shfl(corr1, g * 4 + r);
#pragma unroll
        for (int n = 0; n < 4; ++n) { o0[n][r] *= c0; o1[n][r] *= c1; }
      }
    }
    // ---- P = exp2(S - m): lane-local lsum; pack f16x4 -> ds_write_b64
#pragma unroll
    for (int n = 0; n < 4; ++n) {
      f16x4 pk0, pk1;
#pragma unroll
      for (int r = 0; r < 4; ++r) {
        float p0 = EXP2(sa0[n][r] - m0);
        float p1 = EXP2(sa1[n][r] - m1);
        lsum0 += p0; lsum1 += p1;
        pk0[r] = (f16)p0; pk1[r] = (f16)p1;
      }
      *(f16x4*)(pbase + pw0 + ((n * 32 + g * 8) ^ sw)) = pk0;
      *(f16x4*)(pbase + 2048 + pw0 + ((n * 32 + g * 8) ^ sw)) = pk1;
    }
    asm volatile("s_waitcnt lgkmcnt(0)" ::: "memory");
    f16x8 pa00 = *(const f16x8*)(pbase + pw0 + ((g * 16) ^ sw));
    f16x8 pa01 = *(const f16x8*)(pbase + pw0 + ((64 + g * 16) ^ sw));
    f16x8 pa10 = *(const f16x8*)(pbase + 2048 + pw0 + ((g * 16) ^ sw));
    f16x8 pa11 = *(const f16x8*)(pbase + 2048 + pw0 + ((64 + g * 16) ^ sw));
    // ---- O += P V (V frags shared by both subtiles)
    __builtin_amdgcn_s_setprio(1);
#pragma unroll
    for (int n = 0; n < 4; ++n) {
      int dk = n * 16 + cL;
      f16x8 v0 = *(const f16x8*)&vb[dk * 64 + ((g ^ (dk & 7)) << 3)];
      f16x8 v1 = *(const f16x8*)&vb[dk * 64 + (((g + 4) ^ (dk & 7)) << 3)];
      o0[n] = MFMA16(pa00, v0, o0[n]);
      o0[n] = MFMA16(pa01, v1, o0[n]);
      o1[n] = MFMA16(pa10, v0, o1[n]);
      o1[n] = MFMA16(pa11, v1, o1[n]);
    }
    __builtin_amdgcn_s_setprio(0);
    __syncthreads();
  }
#undef ASTAGE
  // ---- epilogue: finish lsum (row q=cL per subtile), normalize, store
  lsum0 += __shfl_xor(lsum0, 16);
  lsum0 += __shfl_xor(lsum0, 32);
  lsum1 += __shfl_xor(lsum1, 16);
  lsum1 += __shfl_xor(lsum1, 32);
  float inv0 = 1.0f / lsum0, inv1 = 1.0f / lsum1;
  const int qrow0 = qbase + g * 4;
  size_t rowoff = ((size_t)b * 2048 + qrow0) * 1024 + h * 64;
#pragma unroll
  for (int r = 0; r < 4; ++r) {
    float iv0 = __shfl(inv0, g * 4 + r);
    float iv1 = __shfl(inv1, g * 4 + r);
#pragma unroll
    for (int n = 0; n < 4; ++n) {
      Oh[rowoff + (size_t)r * 1024 + n * 16 + cL] = (f16)(o0[n][r] * iv0);
      Oh[rowoff + (size_t)(r + 16) * 1024 + n * 16 + cL] = (f16)(o1[n][r] * iv1);
    }
  }
}

// ---------------------------------------------------------------- launch

extern "C" void kernel_launch(void* const* d_in, const int* in_sizes, int n_in,
                              void* d_out, int out_size, void* d_ws, size_t ws_size,
                              hipStream_t stream) {
  const float* X = (const float*)d_in[0];
  const float* Wq = (const float*)d_in[1];
  const float* Wk = (const float*)d_in[2];
  const float* Wv = (const float*)d_in[3];
  const float* Wo = (const float*)d_in[4];
  const float* relb = (const float*)d_in[5];

  const size_t MB8 = (size_t)8 << 20;
  if (ws_size < 6 * MB8 + (1 << 19)) return;

  char* ws = (char*)d_ws;
  f16* Xh = (f16*)(ws + 0 * MB8);
  f16* Wt = (f16*)(ws + 1 * MB8);
  f16* Qh = (f16*)(ws + 2 * MB8);
  f16* Kh = (f16*)(ws + 3 * MB8);
  f16* Vt = (f16*)(ws + 4 * MB8);
  f16* Oh = (f16*)(ws + 5 * MB8);
  f16* brel = (f16*)(ws + 6 * MB8);  // [16][4096] f16, log2e-scaled

  cast_x_kernel<<<dim3(4096), dim3(256), 0, stream>>>((const float4*)X, (f16x4*)Xh);
  transpose_w_kernel<<<dim3(32, 32, 4), dim3(32, 8), 0, stream>>>(Wq, Wk, Wv, Wo, Wt);
  bias_kernel<<<dim3(256), dim3(256), 0, stream>>>(relb, brel);
  gemm_qkv_kernel<<<dim3(24, 32), dim3(256), 0, stream>>>(Xh, Wt, Qh, Kh, Vt);
  attn_kernel<<<dim3(16, 32), dim3(256), 0, stream>>>(Qh, Kh, Vt, brel, Oh);
  gemm_out_kernel<<<dim3(8, 32), dim3(256), 0, stream>>>(Oh, Wt + (size_t)3072 * 1024,
                                                         (float*)d_out);
}

// Round 7
// 150.063 us; speedup vs baseline: 1.3480x; 1.0318x over previous
//
#include <hip/hip_runtime.h>
#include <math.h>

// B=2, S=2048, D=1024, H=16, DK=64, NUM_BUCKETS=32, MAX_DIST=128, SM_SCALE=0.25
// Softmax in log2 domain: Wq pre-scaled by 0.25*log2(e), bias table pre-scaled by log2(e).
// attn: 32x32x16 MFMA, swapped QK^T (mfma(K,Q)) -> S^T col=q lane-local softmax;
// P redistributed to PV B-fragments IN REGISTERS via cvt_pkrtz + v_permlane32_swap
// (no LDS P roundtrip). T5 bucket saturation skips bias table on 26/32 tiles.

typedef _Float16 f16;
typedef _Float16 f16x4 __attribute__((ext_vector_type(4)));
typedef _Float16 f16x8 __attribute__((ext_vector_type(8)));
typedef float f32x4 __attribute__((ext_vector_type(4)));
typedef float f32x16 __attribute__((ext_vector_type(16)));
typedef unsigned int u32;
typedef u32 u32x4 __attribute__((ext_vector_type(4)));

#define MFMA16(a, b, c) __builtin_amdgcn_mfma_f32_16x16x32_f16((a), (b), (c), 0, 0, 0)
#define MFMA32(a, b, c) __builtin_amdgcn_mfma_f32_32x32x16_f16((a), (b), (c), 0, 0, 0)

static __device__ __forceinline__ float EXP2(float x) {
  float r;
  asm("v_exp_f32 %0, %1" : "=v"(r) : "v"(x));
  return r;
}

// pack two f32 -> f16x2 in a u32 (RTZ)
static __device__ __forceinline__ u32 pk2(float a, float b) {
  return __builtin_bit_cast(u32, __builtin_amdgcn_cvt_pkrtz(a, b));
}
// exchange: a.hi(lanes32-63) <- b.lo(lanes0-31 old), b.lo <- a.hi(old)
static __device__ __forceinline__ void swap32(u32& a, u32& b) {
  asm volatile("v_permlane32_swap_b32 %0, %1" : "+v"(a), "+v"(b));
}

// async global->LDS, 16B per lane; lds base must be wave-uniform (HW adds lane*16)
__device__ __forceinline__ void gload16(const f16* g, f16* l) {
  __builtin_amdgcn_global_load_lds(
      (const __attribute__((address_space(1))) void*)g,
      (__attribute__((address_space(3))) void*)l, 16, 0, 0);
}

// ---------------------------------------------------------------- prep kernels

__global__ __launch_bounds__(256) void cast_x_kernel(const float4* __restrict__ x,
                                                     f16x4* __restrict__ xh) {
  int i = blockIdx.x * 256 + threadIdx.x;
  float4 v = x[i];
  f16x4 o;
  o[0] = (f16)v.x; o[1] = (f16)v.y; o[2] = (f16)v.z; o[3] = (f16)v.w;
  xh[i] = o;
}

// W[k][n] (1024x1024 fp32) -> Wt[z*1024 + n][k] f16; Wq scaled by 0.25*log2e
__global__ void transpose_w_kernel(const float* __restrict__ w0, const float* __restrict__ w1,
                                   const float* __restrict__ w2, const float* __restrict__ w3,
                                   f16* __restrict__ wt) {
  int z = blockIdx.z;
  const float* w = (z == 0) ? w0 : (z == 1) ? w1 : (z == 2) ? w2 : w3;
  float sc = (z == 0) ? 0.36067376022224085f : 1.0f;  // 0.25 * log2(e)
  __shared__ float tile[32][33];
  int tx = threadIdx.x, ty = threadIdx.y;
  int kt = blockIdx.x * 32, nt = blockIdx.y * 32;
#pragma unroll
  for (int i = 0; i < 4; ++i)
    tile[ty + i * 8][tx] = w[(size_t)(kt + ty + i * 8) * 1024 + nt + tx];
  __syncthreads();
#pragma unroll
  for (int i = 0; i < 4; ++i)
    wt[((size_t)z * 1024 + nt + ty + i * 8) * 1024 + kt + tx] = (f16)(tile[tx][ty + i * 8] * sc);
}

// T5 bias table, log2e-scaled, f16, layout [h][4096] with index rp+2048 (rp in [-2047,2047])
__global__ __launch_bounds__(256) void bias_kernel(const float* __restrict__ rel_bias,
                                                   f16* __restrict__ bias_rel) {
  int idx = blockIdx.x * 256 + threadIdx.x;  // 65536 total
  int h = idx >> 12;
  int r = idx & 4095;
  int rp = r - 2048;
  if (rp < -2047) rp = -2047;
  int bucket = (rp > 0) ? 16 : 0;
  int rpa = (rp < 0) ? -rp : rp;
  if (rpa < 8) {
    bucket += rpa;
  } else {
    int large = 8 + (int)(logf((float)rpa / 8.0f) / logf(16.0f) * 8.0f);
    bucket += (large < 15) ? large : 15;
  }
  bias_rel[idx] = (f16)(rel_bias[bucket * 16 + h] * 1.4426950408889634f);
}

// ---------------------------------------------------------------- GEMM 128x128, BK=32
__device__ __forceinline__ void gemm128_core(const f16* __restrict__ A, const f16* __restrict__ Bt,
                                             int mrow, int ncol0, f16* sm /*[2][8192]*/,
                                             f32x4 acc[4][4]) {
  const int t = threadIdx.x;
  const int lane = t & 63, w = t >> 6;
  const int cL = lane & 15, g = lane >> 4;
  const int wr = w >> 1, wc = w & 1;

  const int c0 = w * 128 + lane;
  const int c1 = c0 + 64;
  const int rA0 = c0 >> 2, kA0 = ((c0 & 3) ^ (rA0 & 3)) << 3;
  const int rA1 = c1 >> 2, kA1 = ((c1 & 3) ^ (rA1 & 3)) << 3;
  const f16* gA0 = A + (size_t)(mrow + rA0) * 1024 + kA0;
  const f16* gA1 = A + (size_t)(mrow + rA1) * 1024 + kA1;
  const f16* gB0 = Bt + (size_t)(ncol0 + rA0) * 1024 + kA0;
  const f16* gB1 = Bt + (size_t)(ncol0 + rA1) * 1024 + kA1;
  const int lds0 = (w * 2) * 512, lds1 = (w * 2 + 1) * 512;

#define GSTAGE(buf, k0)                            \
  do {                                             \
    f16* s_ = sm + (buf) * 8192;                   \
    gload16(gA0 + (k0), s_ + lds0);                \
    gload16(gA1 + (k0), s_ + lds1);                \
    gload16(gB0 + (k0), s_ + 4096 + lds0);         \
    gload16(gB1 + (k0), s_ + 4096 + lds1);         \
  } while (0)

  GSTAGE(0, 0);
  __syncthreads();
#pragma unroll 2
  for (int ks = 0; ks < 32; ++ks) {
    const int cur = ks & 1;
    if (ks < 31) GSTAGE(cur ^ 1, (ks + 1) * 32);
    const f16* bA = sm + cur * 8192;
    const f16* bB = bA + 4096;
    f16x8 af[4], bf[4];
#pragma unroll
    for (int m = 0; m < 4; ++m) {
      int r = wr * 64 + m * 16 + cL;
      af[m] = *(const f16x8*)&bA[r * 32 + ((g ^ (r & 3)) << 3)];
    }
#pragma unroll
    for (int n = 0; n < 4; ++n) {
      int r = wc * 64 + n * 16 + cL;
      bf[n] = *(const f16x8*)&bB[r * 32 + ((g ^ (r & 3)) << 3)];
    }
#pragma unroll
    for (int m = 0; m < 4; ++m)
#pragma unroll
      for (int n = 0; n < 4; ++n) acc[m][n] = MFMA16(af[m], bf[n], acc[m][n]);
    __syncthreads();
  }
#undef GSTAGE
}

// QKV projection -> Q,K [b][h][s][dk], V^T [b][h][dk][s]
__global__ __launch_bounds__(256) void gemm_qkv_kernel(const f16* __restrict__ Xh,
                                                       const f16* __restrict__ Wt,
                                                       f16* __restrict__ Qh,
                                                       f16* __restrict__ Kh,
                                                       f16* __restrict__ Vt) {
  __shared__ __align__(16) f16 sm[2][8192];
  int mrow = blockIdx.y * 128, ncol0 = blockIdx.x * 128;
  f32x4 acc[4][4] = {};
  gemm128_core(Xh, Wt, mrow, ncol0, &sm[0][0], acc);
  int lane = threadIdx.x & 63, w = threadIdx.x >> 6;
  int cL = lane & 15, g = lane >> 4;
  int wr = w >> 1, wc = w & 1;
  int which = (ncol0 + wc * 64) >> 10;
#pragma unroll
  for (int m = 0; m < 4; ++m) {
#pragma unroll
    for (int n = 0; n < 4; ++n) {
#pragma unroll
      for (int r = 0; r < 4; ++r) {
        int tt = mrow + wr * 64 + m * 16 + g * 4 + r;
        int b = tt >> 11, s = tt & 2047;
        int col = (ncol0 + wc * 64 + n * 16 + cL) & 1023;
        int hh = col >> 6, dk = col & 63;
        f16 val = (f16)acc[m][n][r];
        if (which == 0)
          Qh[(((size_t)b * 16 + hh) * 2048 + s) * 64 + dk] = val;
        else if (which == 1)
          Kh[(((size_t)b * 16 + hh) * 2048 + s) * 64 + dk] = val;
        else
          Vt[(((size_t)b * 16 + hh) * 64 + dk) * 2048 + s] = val;
      }
    }
  }
}

// Output projection -> fp32 d_out
__global__ __launch_bounds__(256) void gemm_out_kernel(const f16* __restrict__ Oh,
                                                       const f16* __restrict__ WoT,
                                                       float* __restrict__ out) {
  __shared__ __align__(16) f16 sm[2][8192];
  int mrow = blockIdx.y * 128, ncol0 = blockIdx.x * 128;
  f32x4 acc[4][4] = {};
  gemm128_core(Oh, WoT, mrow, ncol0, &sm[0][0], acc);
  int lane = threadIdx.x & 63, w = threadIdx.x >> 6;
  int cL = lane & 15, g = lane >> 4;
  int wr = w >> 1, wc = w & 1;
#pragma unroll
  for (int m = 0; m < 4; ++m)
#pragma unroll
    for (int n = 0; n < 4; ++n)
#pragma unroll
      for (int r = 0; r < 4; ++r) {
        int tt = mrow + wr * 64 + m * 16 + g * 4 + r;
        out[(size_t)tt * 1024 + ncol0 + wc * 64 + n * 16 + cL] = acc[m][n][r];
      }
}

// ---------------------------------------------------------------- attention
// Grid (S/128, B*H), 4 waves/block, each wave 32 q-rows via 32x32 MFMA.
// S^T = mfma32(K,Q): lane holds S^T[key=(reg&3)+8(reg>>2)+4hi+32ks][q=lo5].
// P -> PV B-frags in registers: pack pairs (cvt_pkrtz) + v_permlane32_swap.
// O^T = mfma32(V^T, P^T): lane holds O^T[dk][q=lo5] -> lane-local normalize.
__global__ __launch_bounds__(256) void attn_kernel(const f16* __restrict__ Qh,
                                                   const f16* __restrict__ Kh,
                                                   const f16* __restrict__ Vt,
                                                   const f16* __restrict__ bias_rel,
                                                   f16* __restrict__ Oh) {
  __shared__ __align__(16) f16 sKV[2][8192];  // [buf][ K 4096 | V 4096 ] f16
  __shared__ __align__(16) f16 sB[2176];      // bias slice (f16, log2e-scaled)
  int bh = blockIdx.y;
  int h = bh & 15, b = bh >> 4;
  int qt = blockIdx.x * 128;
  int t = threadIdx.x;
  int lane = t & 63, wave = t >> 6;
  int lo5 = lane & 31, hi = lane >> 5;
  const size_t bhS = (size_t)bh * 2048;
  const int qrow = qt + wave * 32 + lo5;  // this lane's q-row (col of S^T/O^T)

  // Q B-fragments: qf[m] = Q[qrow][16m + 8hi .. +7] (Q pre-scaled by 0.25*log2e)
  const f16* qp = Qh + (bhS + qrow) * 64 + hi * 8;
  f16x8 qf[4];
#pragma unroll
  for (int m = 0; m < 4; ++m) qf[m] = *(const f16x8*)(qp + 16 * m);

  // far-tile constants: bucket saturates for |rp| >= 91
  float cpos = (float)bias_rel[(size_t)h * 4096 + 4095];  // rp = +2047
  float cneg = (float)bias_rel[(size_t)h * 4096 + 1];     // rp = -2047

  // stage bias slice: sB[j] = bias_rel[h*4096 + 1920 - qt + j]; bias(q,k)=sB[k-(q-qt)+128]
  {
    const float4* gB = (const float4*)(bias_rel + (size_t)h * 4096 + 1920 - qt);
    for (int i = t; i < 272; i += 256) ((float4*)sB)[i] = gB[i];
  }

  // K/V staging (identical to prior round): pre-swizzled global src, linear LDS dest
  const int rK0 = t >> 3, ccK0 = ((t & 7) ^ (rK0 & 7)) << 3;
  const int rK1 = rK0 + 32, ccK1 = ((t & 7) ^ (rK1 & 7)) << 3;
  const f16* gK0 = Kh + (bhS + rK0) * 64 + ccK0;
  const f16* gK1 = Kh + (bhS + rK1) * 64 + ccK1;
  const f16* gV0 = Vt + ((size_t)bh * 64 + rK0) * 2048 + ccK0;
  const f16* gV1 = Vt + ((size_t)bh * 64 + rK1) * 2048 + ccK1;
  const int ldsA = wave * 512, ldsB = wave * 512 + 2048;

#define ASTAGE(buf, key0)                           \
  do {                                              \
    f16* s_ = &sKV[buf][0];                         \
    gload16(gK0 + (size_t)(key0) * 64, s_ + ldsA);  \
    gload16(gK1 + (size_t)(key0) * 64, s_ + ldsB);  \
    gload16(gV0 + (key0), s_ + 4096 + ldsA);        \
    gload16(gV1 + (key0), s_ + 4096 + ldsB);        \
  } while (0)

  f32x16 o0 = {}, o1 = {};  // O^T[dk][q=lo5]; o0: dk 0-31, o1: dk 32-63
  float m_ = -INFINITY, lsum = 0.f;
  const int sw7 = lo5 & 7;

  ASTAGE(0, 0);
  __syncthreads();
  for (int kt = 0; kt < 32; ++kt) {
    const int cur = kt & 1;
    if (kt < 31) ASTAGE(cur ^ 1, (kt + 1) * 64);
    const int key0 = kt * 64;
    const f16* kb = &sKV[cur][0];
    const f16* vb = kb + 4096;
    const int dkt = key0 - qt;

    // ---- bias C-init: sa[reg] = bias(q=lo5col, key = key0+32ks+(reg&3)+8(reg>>2)+4hi)
    f32x16 sa0, sa1;
    if (dkt >= 256 || dkt <= -192) {
      float c = (dkt > 0) ? cpos : cneg;
#pragma unroll
      for (int i = 0; i < 16; ++i) { sa0[i] = c; sa1[i] = c; }
    } else {
      const int bb = key0 + 4 * hi - wave * 32 - lo5 + 128;
#pragma unroll
      for (int i = 0; i < 16; ++i) {
        int pat = (i & 3) + 8 * (i >> 2);
        sa0[i] = (float)sB[bb + pat];
        sa1[i] = (float)sB[bb + 32 + pat];
      }
    }
    // ---- S^T = K Q^T (swapped operands; A = K rows=keys, B = Q^T cols=q)
    const f16* kr0 = kb + lo5 * 64;
    const f16* kr1 = kb + (32 + lo5) * 64;
    __builtin_amdgcn_s_setprio(1);
#pragma unroll
    for (int m = 0; m < 4; ++m) {
      int c = ((2 * m + hi) ^ sw7) << 3;
      sa0 = MFMA32(*(const f16x8*)(kr0 + c), qf[m], sa0);
      sa1 = MFMA32(*(const f16x8*)(kr1 + c), qf[m], sa1);
    }
    __builtin_amdgcn_s_setprio(0);
    // ---- row max (all 32 lane values share q=lo5; cross-half covers other keys)
    float tm[16];
#pragma unroll
    for (int i = 0; i < 16; ++i) tm[i] = fmaxf(sa0[i], sa1[i]);
#pragma unroll
    for (int s2 = 8; s2; s2 >>= 1)
#pragma unroll
      for (int i = 0; i < 8; ++i)
        if (i < s2) tm[i] = fmaxf(tm[i], tm[i + s2]);
    float mx = fmaxf(tm[0], __shfl_xor(tm[0], 32));
    // ---- defer-max: rescale only when row max grew by > 8 (log2 units); lane-local
    if (__any(mx > m_ + 8.f)) {
      float mn = fmaxf(m_, mx);
      float corr = EXP2(m_ - mn);
      lsum *= corr;
      m_ = mn;
#pragma unroll
      for (int i = 0; i < 16; ++i) { o0[i] *= corr; o1[i] *= corr; }
    }
    // ---- P = exp2(S - m): pack + permlane -> PV B-frags (keys 16mk..16mk+15 each)
    float p[16];
    u32 w0, w1, w2, w3, w4, w5, w6, w7;
#pragma unroll
    for (int i = 0; i < 16; ++i) p[i] = EXP2(sa0[i] - m_);
    w0 = pk2(p[0], p[1]);   w1 = pk2(p[2], p[3]);
    w2 = pk2(p[4], p[5]);   w3 = pk2(p[6], p[7]);
    w4 = pk2(p[8], p[9]);   w5 = pk2(p[10], p[11]);
    w6 = pk2(p[12], p[13]); w7 = pk2(p[14], p[15]);
#pragma unroll
    for (int s2 = 8; s2; s2 >>= 1)
#pragma unroll
      for (int i = 0; i < 8; ++i)
        if (i < s2) p[i] += p[i + s2];
    float ls = p[0];
    swap32(w0, w2); swap32(w1, w3); swap32(w4, w6); swap32(w5, w7);
    f16x8 pb0 = __builtin_bit_cast(f16x8, (u32x4){w0, w1, w2, w3});
    f16x8 pb1 = __builtin_bit_cast(f16x8, (u32x4){w4, w5, w6, w7});
#pragma unroll
    for (int i = 0; i < 16; ++i) p[i] = EXP2(sa1[i] - m_);
    w0 = pk2(p[0], p[1]);   w1 = pk2(p[2], p[3]);
    w2 = pk2(p[4], p[5]);   w3 = pk2(p[6], p[7]);
    w4 = pk2(p[8], p[9]);   w5 = pk2(p[10], p[11]);
    w6 = pk2(p[12], p[13]); w7 = pk2(p[14], p[15]);
#pragma unroll
    for (int s2 = 8; s2; s2 >>= 1)
#pragma unroll
      for (int i = 0; i < 8; ++i)
        if (i < s2) p[i] += p[i + s2];
    lsum += ls + p[0];
    swap32(w0, w2); swap32(w1, w3); swap32(w4, w6); swap32(w5, w7);
    f16x8 pb2 = __builtin_bit_cast(f16x8, (u32x4){w0, w1, w2, w3});
    f16x8 pb3 = __builtin_bit_cast(f16x8, (u32x4){w4, w5, w6, w7});
    // ---- O^T += V^T P^T (A = V^T rows=dk, B = P^T cols=q)
    const f16* vr0 = vb + lo5 * 64;
    const f16* vr1 = vb + (32 + lo5) * 64;
    __builtin_amdgcn_s_setprio(1);
    {
      int c = ((0 + hi) ^ sw7) << 3;
      o0 = MFMA32(*(const f16x8*)(vr0 + c), pb0, o0);
      o1 = MFMA32(*(const f16x8*)(vr1 + c), pb0, o1);
    }
    {
      int c = ((2 + hi) ^ sw7) << 3;
      o0 = MFMA32(*(const f16x8*)(vr0 + c), pb1, o0);
      o1 = MFMA32(*(const f16x8*)(vr1 + c), pb1, o1);
    }
    {
      int c = ((4 + hi) ^ sw7) << 3;
      o0 = MFMA32(*(const f16x8*)(vr0 + c), pb2, o0);
      o1 = MFMA32(*(const f16x8*)(vr1 + c), pb2, o1);
    }
    {
      int c = ((6 + hi) ^ sw7) << 3;
      o0 = MFMA32(*(const f16x8*)(vr0 + c), pb3, o0);
      o1 = MFMA32(*(const f16x8*)(vr1 + c), pb3, o1);
    }
    __builtin_amdgcn_s_setprio(0);
    __syncthreads();
  }
#undef ASTAGE
  // ---- epilogue: lane-local normalize (q=lo5), dk = (reg&3)+8(reg>>2)+4hi (+32 for o1)
  lsum += __shfl_xor(lsum, 32);
  float inv = 1.0f / lsum;
  size_t base = ((size_t)b * 2048 + qrow) * 1024 + h * 64 + 4 * hi;
#pragma unroll
  for (int rq = 0; rq < 4; ++rq) {
    f16x4 v0, v1;
#pragma unroll
    for (int j = 0; j < 4; ++j) {
      v0[j] = (f16)(o0[rq * 4 + j] * inv);
      v1[j] = (f16)(o1[rq * 4 + j] * inv);
    }
    *(f16x4*)&Oh[base + 8 * rq] = v0;
    *(f16x4*)&Oh[base + 32 + 8 * rq] = v1;
  }
}

// ---------------------------------------------------------------- launch

extern "C" void kernel_launch(void* const* d_in, const int* in_sizes, int n_in,
                              void* d_out, int out_size, void* d_ws, size_t ws_size,
                              hipStream_t stream) {
  const float* X = (const float*)d_in[0];
  const float* Wq = (const float*)d_in[1];
  const float* Wk = (const float*)d_in[2];
  const float* Wv = (const float*)d_in[3];
  const float* Wo = (const float*)d_in[4];
  const float* relb = (const float*)d_in[5];

  const size_t MB8 = (size_t)8 << 20;
  if (ws_size < 6 * MB8 + (1 << 19)) return;

  char* ws = (char*)d_ws;
  f16* Xh = (f16*)(ws + 0 * MB8);
  f16* Wt = (f16*)(ws + 1 * MB8);
  f16* Qh = (f16*)(ws + 2 * MB8);
  f16* Kh = (f16*)(ws + 3 * MB8);
  f16* Vt = (f16*)(ws + 4 * MB8);
  f16* Oh = (f16*)(ws + 5 * MB8);
  f16* brel = (f16*)(ws + 6 * MB8);  // [16][4096] f16, log2e-scaled

  cast_x_kernel<<<dim3(4096), dim3(256), 0, stream>>>((const float4*)X, (f16x4*)Xh);
  transpose_w_kernel<<<dim3(32, 32, 4), dim3(32, 8), 0, stream>>>(Wq, Wk, Wv, Wo, Wt);
  bias_kernel<<<dim3(256), dim3(256), 0, stream>>>(relb, brel);
  gemm_qkv_kernel<<<dim3(24, 32), dim3(256), 0, stream>>>(Xh, Wt, Qh, Kh, Vt);
  attn_kernel<<<dim3(16, 32), dim3(256), 0, stream>>>(Qh, Kh, Vt, brel, Oh);
  gemm_out_kernel<<<dim3(8, 32), dim3(256), 0, stream>>>(Oh, Wt + (size_t)3072 * 1024,
                                                         (float*)d_out);
}

// Round 8
// 148.933 us; speedup vs baseline: 1.3582x; 1.0076x over previous
//
#include <hip/hip_runtime.h>
#include <math.h>

// B=2, S=2048, D=1024, H=16, DK=64, NUM_BUCKETS=32, MAX_DIST=128, SM_SCALE=0.25
// Softmax in log2 domain: Wq pre-scaled by 0.25*log2(e), bias table pre-scaled by log2(e).
// attn: 32x32x16 MFMA, swapped QK^T; in-register P redistribution (cvt_pkrtz+permlane32);
// 4-buffer LDS pipeline w/ counted vmcnt (never 0 in steady state) + raw s_barrier;
// XCD-swizzled block mapping so each head's K/V stays in one XCD's L2.

typedef _Float16 f16;
typedef _Float16 f16x4 __attribute__((ext_vector_type(4)));
typedef _Float16 f16x8 __attribute__((ext_vector_type(8)));
typedef float f32x4 __attribute__((ext_vector_type(4)));
typedef float f32x16 __attribute__((ext_vector_type(16)));
typedef unsigned int u32;
typedef u32 u32x4 __attribute__((ext_vector_type(4)));

#define MFMA16(a, b, c) __builtin_amdgcn_mfma_f32_16x16x32_f16((a), (b), (c), 0, 0, 0)
#define MFMA32(a, b, c) __builtin_amdgcn_mfma_f32_32x32x16_f16((a), (b), (c), 0, 0, 0)

static __device__ __forceinline__ float EXP2(float x) {
  float r;
  asm("v_exp_f32 %0, %1" : "=v"(r) : "v"(x));
  return r;
}

// pack two f32 -> f16x2 in a u32 (RTZ)
static __device__ __forceinline__ u32 pk2(float a, float b) {
  return __builtin_bit_cast(u32, __builtin_amdgcn_cvt_pkrtz(a, b));
}
// exchange: a.hi(lanes32-63) <- b.lo(lanes0-31 old), b.lo <- a.hi(old)
static __device__ __forceinline__ void swap32(u32& a, u32& b) {
  asm volatile("v_permlane32_swap_b32 %0, %1" : "+v"(a), "+v"(b));
}

// force a loaded value resident NOW (makes the waitcnt pass retire its vmcnt in
// the prologue instead of conservatively draining inside the pipelined loop)
#define KEEPV8(v8)                                                        \
  do {                                                                    \
    u32x4 _t = __builtin_bit_cast(u32x4, (v8));                           \
    asm volatile("" ::"v"(_t[0]), "v"(_t[1]), "v"(_t[2]), "v"(_t[3]));    \
  } while (0)

// async global->LDS, 16B per lane; lds base must be wave-uniform (HW adds lane*16)
__device__ __forceinline__ void gload16(const f16* g, f16* l) {
  __builtin_amdgcn_global_load_lds(
      (const __attribute__((address_space(1))) void*)g,
      (__attribute__((address_space(3))) void*)l, 16, 0, 0);
}

// ---------------------------------------------------------------- prep kernels

__global__ __launch_bounds__(256) void cast_x_kernel(const float4* __restrict__ x,
                                                     f16x4* __restrict__ xh) {
  int i = blockIdx.x * 256 + threadIdx.x;
  float4 v = x[i];
  f16x4 o;
  o[0] = (f16)v.x; o[1] = (f16)v.y; o[2] = (f16)v.z; o[3] = (f16)v.w;
  xh[i] = o;
}

// W[k][n] (1024x1024 fp32) -> Wt[z*1024 + n][k] f16; Wq scaled by 0.25*log2e
__global__ void transpose_w_kernel(const float* __restrict__ w0, const float* __restrict__ w1,
                                   const float* __restrict__ w2, const float* __restrict__ w3,
                                   f16* __restrict__ wt) {
  int z = blockIdx.z;
  const float* w = (z == 0) ? w0 : (z == 1) ? w1 : (z == 2) ? w2 : w3;
  float sc = (z == 0) ? 0.36067376022224085f : 1.0f;  // 0.25 * log2(e)
  __shared__ float tile[32][33];
  int tx = threadIdx.x, ty = threadIdx.y;
  int kt = blockIdx.x * 32, nt = blockIdx.y * 32;
#pragma unroll
  for (int i = 0; i < 4; ++i)
    tile[ty + i * 8][tx] = w[(size_t)(kt + ty + i * 8) * 1024 + nt + tx];
  __syncthreads();
#pragma unroll
  for (int i = 0; i < 4; ++i)
    wt[((size_t)z * 1024 + nt + ty + i * 8) * 1024 + kt + tx] = (f16)(tile[tx][ty + i * 8] * sc);
}

// T5 bias table, log2e-scaled, f16, layout [h][4096] with index rp+2048 (rp in [-2047,2047])
__global__ __launch_bounds__(256) void bias_kernel(const float* __restrict__ rel_bias,
                                                   f16* __restrict__ bias_rel) {
  int idx = blockIdx.x * 256 + threadIdx.x;  // 65536 total
  int h = idx >> 12;
  int r = idx & 4095;
  int rp = r - 2048;
  if (rp < -2047) rp = -2047;
  int bucket = (rp > 0) ? 16 : 0;
  int rpa = (rp < 0) ? -rp : rp;
  if (rpa < 8) {
    bucket += rpa;
  } else {
    int large = 8 + (int)(logf((float)rpa / 8.0f) / logf(16.0f) * 8.0f);
    bucket += (large < 15) ? large : 15;
  }
  bias_rel[idx] = (f16)(rel_bias[bucket * 16 + h] * 1.4426950408889634f);
}

// ---------------------------------------------------------------- GEMM 128x128, BK=32
__device__ __forceinline__ void gemm128_core(const f16* __restrict__ A, const f16* __restrict__ Bt,
                                             int mrow, int ncol0, f16* sm /*[2][8192]*/,
                                             f32x4 acc[4][4]) {
  const int t = threadIdx.x;
  const int lane = t & 63, w = t >> 6;
  const int cL = lane & 15, g = lane >> 4;
  const int wr = w >> 1, wc = w & 1;

  const int c0 = w * 128 + lane;
  const int c1 = c0 + 64;
  const int rA0 = c0 >> 2, kA0 = ((c0 & 3) ^ (rA0 & 3)) << 3;
  const int rA1 = c1 >> 2, kA1 = ((c1 & 3) ^ (rA1 & 3)) << 3;
  const f16* gA0 = A + (size_t)(mrow + rA0) * 1024 + kA0;
  const f16* gA1 = A + (size_t)(mrow + rA1) * 1024 + kA1;
  const f16* gB0 = Bt + (size_t)(ncol0 + rA0) * 1024 + kA0;
  const f16* gB1 = Bt + (size_t)(ncol0 + rA1) * 1024 + kA1;
  const int lds0 = (w * 2) * 512, lds1 = (w * 2 + 1) * 512;

#define GSTAGE(buf, k0)                            \
  do {                                             \
    f16* s_ = sm + (buf) * 8192;                   \
    gload16(gA0 + (k0), s_ + lds0);                \
    gload16(gA1 + (k0), s_ + lds1);                \
    gload16(gB0 + (k0), s_ + 4096 + lds0);         \
    gload16(gB1 + (k0), s_ + 4096 + lds1);         \
  } while (0)

  GSTAGE(0, 0);
  __syncthreads();
#pragma unroll 2
  for (int ks = 0; ks < 32; ++ks) {
    const int cur = ks & 1;
    if (ks < 31) GSTAGE(cur ^ 1, (ks + 1) * 32);
    const f16* bA = sm + cur * 8192;
    const f16* bB = bA + 4096;
    f16x8 af[4], bf[4];
#pragma unroll
    for (int m = 0; m < 4; ++m) {
      int r = wr * 64 + m * 16 + cL;
      af[m] = *(const f16x8*)&bA[r * 32 + ((g ^ (r & 3)) << 3)];
    }
#pragma unroll
    for (int n = 0; n < 4; ++n) {
      int r = wc * 64 + n * 16 + cL;
      bf[n] = *(const f16x8*)&bB[r * 32 + ((g ^ (r & 3)) << 3)];
    }
#pragma unroll
    for (int m = 0; m < 4; ++m)
#pragma unroll
      for (int n = 0; n < 4; ++n) acc[m][n] = MFMA16(af[m], bf[n], acc[m][n]);
    __syncthreads();
  }
#undef GSTAGE
}

// QKV projection -> Q,K [b][h][s][dk], V^T [b][h][dk][s]
__global__ __launch_bounds__(256) void gemm_qkv_kernel(const f16* __restrict__ Xh,
                                                       const f16* __restrict__ Wt,
                                                       f16* __restrict__ Qh,
                                                       f16* __restrict__ Kh,
                                                       f16* __restrict__ Vt) {
  __shared__ __align__(16) f16 sm[2][8192];
  int mrow = blockIdx.y * 128, ncol0 = blockIdx.x * 128;
  f32x4 acc[4][4] = {};
  gemm128_core(Xh, Wt, mrow, ncol0, &sm[0][0], acc);
  int lane = threadIdx.x & 63, w = threadIdx.x >> 6;
  int cL = lane & 15, g = lane >> 4;
  int wr = w >> 1, wc = w & 1;
  int which = (ncol0 + wc * 64) >> 10;
#pragma unroll
  for (int m = 0; m < 4; ++m) {
#pragma unroll
    for (int n = 0; n < 4; ++n) {
#pragma unroll
      for (int r = 0; r < 4; ++r) {
        int tt = mrow + wr * 64 + m * 16 + g * 4 + r;
        int b = tt >> 11, s = tt & 2047;
        int col = (ncol0 + wc * 64 + n * 16 + cL) & 1023;
        int hh = col >> 6, dk = col & 63;
        f16 val = (f16)acc[m][n][r];
        if (which == 0)
          Qh[(((size_t)b * 16 + hh) * 2048 + s) * 64 + dk] = val;
        else if (which == 1)
          Kh[(((size_t)b * 16 + hh) * 2048 + s) * 64 + dk] = val;
        else
          Vt[(((size_t)b * 16 + hh) * 64 + dk) * 2048 + s] = val;
      }
    }
  }
}

// Output projection -> fp32 d_out
__global__ __launch_bounds__(256) void gemm_out_kernel(const f16* __restrict__ Oh,
                                                       const f16* __restrict__ WoT,
                                                       float* __restrict__ out) {
  __shared__ __align__(16) f16 sm[2][8192];
  int mrow = blockIdx.y * 128, ncol0 = blockIdx.x * 128;
  f32x4 acc[4][4] = {};
  gemm128_core(Oh, WoT, mrow, ncol0, &sm[0][0], acc);
  int lane = threadIdx.x & 63, w = threadIdx.x >> 6;
  int cL = lane & 15, g = lane >> 4;
  int wr = w >> 1, wc = w & 1;
#pragma unroll
  for (int m = 0; m < 4; ++m)
#pragma unroll
    for (int n = 0; n < 4; ++n)
#pragma unroll
      for (int r = 0; r < 4; ++r) {
        int tt = mrow + wr * 64 + m * 16 + g * 4 + r;
        out[(size_t)tt * 1024 + ncol0 + wc * 64 + n * 16 + cL] = acc[m][n][r];
      }
}

// ---------------------------------------------------------------- attention
// 1-D grid 512 blocks, XCD-swizzled: logical L = (bid%8)*64 + bid/8; bh = L/16,
// qt = (L%16)*128 -> all 16 q-blocks of one head on one XCD (K/V L2-resident).
// 4 waves/block, 32 q-rows/wave via 32x32 MFMA. 4 LDS K/V buffers, prefetch depth 2,
// counted vmcnt(8/4/0) + raw s_barrier (one per tile; never a full drain mid-loop).
__global__ __launch_bounds__(256) void attn_kernel(const f16* __restrict__ Qh,
                                                   const f16* __restrict__ Kh,
                                                   const f16* __restrict__ Vt,
                                                   const f16* __restrict__ bias_rel,
                                                   f16* __restrict__ Oh) {
  __shared__ __align__(16) f16 sKV[4][8192];  // [buf][ K 4096 | V 4096 ] f16
  __shared__ __align__(16) f16 sB[2176];      // bias slice (f16, log2e-scaled)
  const int p = blockIdx.x;
  const int L = ((p & 7) << 6) + (p >> 3);
  const int bh = L >> 4;
  const int qt = (L & 15) << 7;
  const int h = bh & 15, b = bh >> 4;
  int t = threadIdx.x;
  int lane = t & 63, wave = t >> 6;
  int lo5 = lane & 31, hi = lane >> 5;
  const size_t bhS = (size_t)bh * 2048;
  const int qrow = qt + wave * 32 + lo5;  // this lane's q-row (col of S^T/O^T)

  // Q B-fragments: qf[m] = Q[qrow][16m + 8hi .. +7] (Q pre-scaled by 0.25*log2e)
  const f16* qp = Qh + (bhS + qrow) * 64 + hi * 8;
  f16x8 qf[4];
#pragma unroll
  for (int m = 0; m < 4; ++m) qf[m] = *(const f16x8*)(qp + 16 * m);

  // far-tile constants: bucket saturates for |rp| >= 91
  float cpos = (float)bias_rel[(size_t)h * 4096 + 4095];  // rp = +2047
  float cneg = (float)bias_rel[(size_t)h * 4096 + 1];     // rp = -2047

  // retire the above loads' vmcnt NOW (before any pipelined stage is issued)
#pragma unroll
  for (int m = 0; m < 4; ++m) KEEPV8(qf[m]);
  asm volatile("" ::"v"(cpos), "v"(cneg));

  // stage bias slice: sB[j] = bias_rel[h*4096 + 1920 - qt + j]; bias(q,k)=sB[k-(q-qt)+128]
  {
    const float4* gB = (const float4*)(bias_rel + (size_t)h * 4096 + 1920 - qt);
    for (int i = t; i < 272; i += 256) ((float4*)sB)[i] = gB[i];
  }

  // K/V staging: pre-swizzled global src, linear LDS dest (16B chunks)
  const int rK0 = t >> 3, ccK0 = ((t & 7) ^ (rK0 & 7)) << 3;
  const int rK1 = rK0 + 32, ccK1 = ((t & 7) ^ (rK1 & 7)) << 3;
  const f16* gK0 = Kh + (bhS + rK0) * 64 + ccK0;
  const f16* gK1 = Kh + (bhS + rK1) * 64 + ccK1;
  const f16* gV0 = Vt + ((size_t)bh * 64 + rK0) * 2048 + ccK0;
  const f16* gV1 = Vt + ((size_t)bh * 64 + rK1) * 2048 + ccK1;
  const int ldsA = wave * 512, ldsB = wave * 512 + 2048;

#define ASTAGE(buf, key0)                           \
  do {                                              \
    f16* s_ = &sKV[buf][0];                         \
    gload16(gK0 + (size_t)(key0) * 64, s_ + ldsA);  \
    gload16(gK1 + (size_t)(key0) * 64, s_ + ldsB);  \
    gload16(gV0 + (key0), s_ + 4096 + ldsA);        \
    gload16(gV1 + (key0), s_ + 4096 + ldsB);        \
  } while (0)

  f32x16 o0 = {}, o1 = {};  // O^T[dk][q=lo5]; o0: dk 0-31, o1: dk 32-63
  float m_ = -INFINITY, lsum = 0.f;
  const int sw7 = lo5 & 7;

  // prologue: two tiles in flight; drain own ds_writes (sB) before first barrier
  ASTAGE(0, 0);
  ASTAGE(1, 64);
  asm volatile("s_waitcnt lgkmcnt(0)" ::: "memory");

  for (int kt = 0; kt < 32; ++kt) {
    if (kt < 30) ASTAGE((kt + 2) & 3, (kt + 2) * 64);
    // wait for OWN stage(kt) (4 loads per younger tile stay in flight), then sync
    if (kt < 30)
      asm volatile("s_waitcnt vmcnt(8)" ::: "memory");
    else if (kt == 30)
      asm volatile("s_waitcnt vmcnt(4)" ::: "memory");
    else
      asm volatile("s_waitcnt vmcnt(0)" ::: "memory");
    __builtin_amdgcn_s_barrier();

    const int key0 = kt * 64;
    const f16* kb = &sKV[kt & 3][0];
    const f16* vb = kb + 4096;
    const int dkt = key0 - qt;

    // ---- bias C-init: sa[reg] = bias(q=lo5col, key = key0+32ks+(reg&3)+8(reg>>2)+4hi)
    f32x16 sa0, sa1;
    if (dkt >= 256 || dkt <= -192) {
      float c = (dkt > 0) ? cpos : cneg;
#pragma unroll
      for (int i = 0; i < 16; ++i) { sa0[i] = c; sa1[i] = c; }
    } else {
      const int bb = key0 + 4 * hi - wave * 32 - lo5 + 128;
#pragma unroll
      for (int i = 0; i < 16; ++i) {
        int pat = (i & 3) + 8 * (i >> 2);
        sa0[i] = (float)sB[bb + pat];
        sa1[i] = (float)sB[bb + 32 + pat];
      }
    }
    // ---- S^T = K Q^T (swapped operands; A = K rows=keys, B = Q^T cols=q)
    const f16* kr0 = kb + lo5 * 64;
    const f16* kr1 = kb + (32 + lo5) * 64;
    __builtin_amdgcn_s_setprio(1);
#pragma unroll
    for (int m = 0; m < 4; ++m) {
      int c = ((2 * m + hi) ^ sw7) << 3;
      sa0 = MFMA32(*(const f16x8*)(kr0 + c), qf[m], sa0);
      sa1 = MFMA32(*(const f16x8*)(kr1 + c), qf[m], sa1);
    }
    __builtin_amdgcn_s_setprio(0);
    // ---- row max (all 32 lane values share q=lo5; cross-half covers other keys)
    float tm[16];
#pragma unroll
    for (int i = 0; i < 16; ++i) tm[i] = fmaxf(sa0[i], sa1[i]);
#pragma unroll
    for (int s2 = 8; s2; s2 >>= 1)
#pragma unroll
      for (int i = 0; i < 8; ++i)
        if (i < s2) tm[i] = fmaxf(tm[i], tm[i + s2]);
    float mx = fmaxf(tm[0], __shfl_xor(tm[0], 32));
    // ---- defer-max: rescale only when row max grew by > 8 (log2 units); lane-local
    if (__any(mx > m_ + 8.f)) {
      float mn = fmaxf(m_, mx);
      float corr = EXP2(m_ - mn);
      lsum *= corr;
      m_ = mn;
#pragma unroll
      for (int i = 0; i < 16; ++i) { o0[i] *= corr; o1[i] *= corr; }
    }
    // ---- P = exp2(S - m): pack + permlane -> PV B-frags (keys 16mk..16mk+15 each)
    float pr[16];
    u32 w0, w1, w2, w3, w4, w5, w6, w7;
#pragma unroll
    for (int i = 0; i < 16; ++i) pr[i] = EXP2(sa0[i] - m_);
    w0 = pk2(pr[0], pr[1]);   w1 = pk2(pr[2], pr[3]);
    w2 = pk2(pr[4], pr[5]);   w3 = pk2(pr[6], pr[7]);
    w4 = pk2(pr[8], pr[9]);   w5 = pk2(pr[10], pr[11]);
    w6 = pk2(pr[12], pr[13]); w7 = pk2(pr[14], pr[15]);
#pragma unroll
    for (int s2 = 8; s2; s2 >>= 1)
#pragma unroll
      for (int i = 0; i < 8; ++i)
        if (i < s2) pr[i] += pr[i + s2];
    float ls = pr[0];
    swap32(w0, w2); swap32(w1, w3); swap32(w4, w6); swap32(w5, w7);
    f16x8 pb0 = __builtin_bit_cast(f16x8, (u32x4){w0, w1, w2, w3});
    f16x8 pb1 = __builtin_bit_cast(f16x8, (u32x4){w4, w5, w6, w7});
#pragma unroll
    for (int i = 0; i < 16; ++i) pr[i] = EXP2(sa1[i] - m_);
    w0 = pk2(pr[0], pr[1]);   w1 = pk2(pr[2], pr[3]);
    w2 = pk2(pr[4], pr[5]);   w3 = pk2(pr[6], pr[7]);
    w4 = pk2(pr[8], pr[9]);   w5 = pk2(pr[10], pr[11]);
    w6 = pk2(pr[12], pr[13]); w7 = pk2(pr[14], pr[15]);
#pragma unroll
    for (int s2 = 8; s2; s2 >>= 1)
#pragma unroll
      for (int i = 0; i < 8; ++i)
        if (i < s2) pr[i] += pr[i + s2];
    lsum += ls + pr[0];
    swap32(w0, w2); swap32(w1, w3); swap32(w4, w6); swap32(w5, w7);
    f16x8 pb2 = __builtin_bit_cast(f16x8, (u32x4){w0, w1, w2, w3});
    f16x8 pb3 = __builtin_bit_cast(f16x8, (u32x4){w4, w5, w6, w7});
    // ---- O^T += V^T P^T (A = V^T rows=dk, B = P^T cols=q)
    const f16* vr0 = vb + lo5 * 64;
    const f16* vr1 = vb + (32 + lo5) * 64;
    __builtin_amdgcn_s_setprio(1);
    {
      int c = ((0 + hi) ^ sw7) << 3;
      o0 = MFMA32(*(const f16x8*)(vr0 + c), pb0, o0);
      o1 = MFMA32(*(const f16x8*)(vr1 + c), pb0, o1);
    }
    {
      int c = ((2 + hi) ^ sw7) << 3;
      o0 = MFMA32(*(const f16x8*)(vr0 + c), pb1, o0);
      o1 = MFMA32(*(const f16x8*)(vr1 + c), pb1, o1);
    }
    {
      int c = ((4 + hi) ^ sw7) << 3;
      o0 = MFMA32(*(const f16x8*)(vr0 + c), pb2, o0);
      o1 = MFMA32(*(const f16x8*)(vr1 + c), pb2, o1);
    }
    {
      int c = ((6 + hi) ^ sw7) << 3;
      o0 = MFMA32(*(const f16x8*)(vr0 + c), pb3, o0);
      o1 = MFMA32(*(const f16x8*)(vr1 + c), pb3, o1);
    }
    __builtin_amdgcn_s_setprio(0);
    // no end-of-tile barrier: 4 buffers + per-iter barrier above make reuse safe
  }
#undef ASTAGE
  // ---- epilogue: lane-local normalize (q=lo5), dk = (reg&3)+8(reg>>2)+4hi (+32 for o1)
  lsum += __shfl_xor(lsum, 32);
  float inv = 1.0f / lsum;
  size_t base = ((size_t)b * 2048 + qrow) * 1024 + h * 64 + 4 * hi;
#pragma unroll
  for (int rq = 0; rq < 4; ++rq) {
    f16x4 v0, v1;
#pragma unroll
    for (int j = 0; j < 4; ++j) {
      v0[j] = (f16)(o0[rq * 4 + j] * inv);
      v1[j] = (f16)(o1[rq * 4 + j] * inv);
    }
    *(f16x4*)&Oh[base + 8 * rq] = v0;
    *(f16x4*)&Oh[base + 32 + 8 * rq] = v1;
  }
}

// ---------------------------------------------------------------- launch

extern "C" void kernel_launch(void* const* d_in, const int* in_sizes, int n_in,
                              void* d_out, int out_size, void* d_ws, size_t ws_size,
                              hipStream_t stream) {
  const float* X = (const float*)d_in[0];
  const float* Wq = (const float*)d_in[1];
  const float* Wk = (const float*)d_in[2];
  const float* Wv = (const float*)d_in[3];
  const float* Wo = (const float*)d_in[4];
  const float* relb = (const float*)d_in[5];

  const size_t MB8 = (size_t)8 << 20;
  if (ws_size < 6 * MB8 + (1 << 19)) return;

  char* ws = (char*)d_ws;
  f16* Xh = (f16*)(ws + 0 * MB8);
  f16* Wt = (f16*)(ws + 1 * MB8);
  f16* Qh = (f16*)(ws + 2 * MB8);
  f16* Kh = (f16*)(ws + 3 * MB8);
  f16* Vt = (f16*)(ws + 4 * MB8);
  f16* Oh = (f16*)(ws + 5 * MB8);
  f16* brel = (f16*)(ws + 6 * MB8);  // [16][4096] f16, log2e-scaled

  cast_x_kernel<<<dim3(4096), dim3(256), 0, stream>>>((const float4*)X, (f16x4*)Xh);
  transpose_w_kernel<<<dim3(32, 32, 4), dim3(32, 8), 0, stream>>>(Wq, Wk, Wv, Wo, Wt);
  bias_kernel<<<dim3(256), dim3(256), 0, stream>>>(relb, brel);
  gemm_qkv_kernel<<<dim3(24, 32), dim3(256), 0, stream>>>(Xh, Wt, Qh, Kh, Vt);
  attn_kernel<<<dim3(512), dim3(256), 0, stream>>>(Qh, Kh, Vt, brel, Oh);
  gemm_out_kernel<<<dim3(8, 32), dim3(256), 0, stream>>>(Oh, Wt + (size_t)3072 * 1024,
                                                         (float*)d_out);
}